// Round 2
// baseline (2139.846 us; speedup 1.0000x reference)
//
#include <hip/hip_runtime.h>
#include <hip/hip_bf16.h>

typedef __hip_bfloat16 bf16;

__device__ __forceinline__ float b2f(bf16 x) { return __bfloat162float(x); }
__device__ __forceinline__ bf16  f2b(float x) { return __float2bfloat16(x); }

// ---------------------------------------------------------------------------
// Bilinear 2x upsample, half-pixel centers, edge clamp (matches reference).
// in/out fp32.
// ---------------------------------------------------------------------------
__global__ void upsample2x_k(const float* __restrict__ in, float* __restrict__ out,
                             int B, int H, int W) {
    const int OH = 2 * H, OW = 2 * W;
    const long total = (long)B * OH * OW;
    long i = (long)blockIdx.x * blockDim.x + threadIdx.x;
    if (i >= total) return;
    int ox = (int)(i % OW);
    long r = i / OW;
    int oy = (int)(r % OH);
    int b  = (int)(r / OH);
    float sy = fminf(fmaxf(oy * 0.5f - 0.25f, 0.0f), (float)(H - 1));
    float sx = fminf(fmaxf(ox * 0.5f - 0.25f, 0.0f), (float)(W - 1));
    int y0 = (int)sy; float ty = sy - (float)y0; int y1 = min(y0 + 1, H - 1);
    int x0 = (int)sx; float tx = sx - (float)x0; int x1 = min(x0 + 1, W - 1);
    const float* p = in + (size_t)b * H * W;
    float v00 = p[(size_t)y0 * W + x0];
    float v01 = p[(size_t)y0 * W + x1];
    float v10 = p[(size_t)y1 * W + x0];
    float v11 = p[(size_t)y1 * W + x1];
    float v = (v00 * (1.f - ty) + v10 * ty) * (1.f - tx)
            + (v01 * (1.f - ty) + v11 * ty) * tx;
    out[i] = v;
}

// ---------------------------------------------------------------------------
// disco conv: gather 8 neighbors, z[c][k] = sum_n g*psi_val, y[o]=sum z*w + b,
// relu. ch0 = upsampled (fp32), ch1 = elev (fp32). out: [B][64][P] bf16.
// One thread handles pixel p for ALL 4 batches: psi_idx/psi_val held in regs
// across b (4x fewer psi_val HBM reads).
// ---------------------------------------------------------------------------
__global__ __launch_bounds__(256)
void disco_k(const float* __restrict__ ch0, const float* __restrict__ ch1,
             const int* __restrict__ psi_idx, const float* __restrict__ psi_val,
             const float* __restrict__ w, const float* __restrict__ bias,
             bf16* __restrict__ out, int P) {
    __shared__ float wl[64 * 18];
    __shared__ float bl[64];
    for (int l = threadIdx.x; l < 64 * 18; l += 256) wl[l] = w[l];
    if (threadIdx.x < 64) bl[threadIdx.x] = bias[threadIdx.x];
    __syncthreads();
    int p = blockIdx.x * 256 + threadIdx.x;
    if (p >= P) return;

    const int* ip = psi_idx + (size_t)p * 8;
    int4 ia = *(const int4*)ip;
    int4 ib = *(const int4*)(ip + 4);
    int idx[8] = {ia.x, ia.y, ia.z, ia.w, ib.x, ib.y, ib.z, ib.w};

    float pv[9][8];
    #pragma unroll
    for (int k = 0; k < 9; k++) {
        const float* q = psi_val + ((size_t)k * P + p) * 8;
        float4 qa = *(const float4*)q;
        float4 qb = *(const float4*)(q + 4);
        pv[k][0] = qa.x; pv[k][1] = qa.y; pv[k][2] = qa.z; pv[k][3] = qa.w;
        pv[k][4] = qb.x; pv[k][5] = qb.y; pv[k][6] = qb.z; pv[k][7] = qb.w;
    }

    for (int b = 0; b < 4; b++) {
        const float* c0 = ch0 + (size_t)b * P;
        const float* c1 = ch1 + (size_t)b * P;
        float g0[8], g1[8];
        #pragma unroll
        for (int n = 0; n < 8; n++) { g0[n] = c0[idx[n]]; g1[n] = c1[idx[n]]; }

        float z[18];
        #pragma unroll
        for (int j = 0; j < 18; j++) z[j] = 0.f;
        #pragma unroll
        for (int k = 0; k < 9; k++) {
            #pragma unroll
            for (int n = 0; n < 8; n++) {
                z[k]     = fmaf(g0[n], pv[k][n], z[k]);
                z[9 + k] = fmaf(g1[n], pv[k][n], z[9 + k]);
            }
        }
        size_t ob = (size_t)b * 64 * P + p;
        for (int o = 0; o < 64; o++) {
            float acc = bl[o];
            #pragma unroll
            for (int j = 0; j < 18; j++) acc = fmaf(z[j], wl[o * 18 + j], acc);
            out[ob + (size_t)o * P] = f2b(fmaxf(acc, 0.f));
        }
    }
}

// ---------------------------------------------------------------------------
// conv2: 5x5 SAME, IC=64 -> OC=32, + bias + relu. bf16 in/out, fp32 accum.
// Block: 256 thr, tile 32x x 8y. Thread: 4 px x 8 oc. LDS: input slab (fp32,
// stride 40 -> 2-way bank alias = free) + weights [ic][tap][oc] fp32.
// IC chunked by 8 -> 40 KB LDS/WG.
// ---------------------------------------------------------------------------
__global__ __launch_bounds__(256, 2)
void conv2_k(const bf16* __restrict__ in, const float* __restrict__ wt,
             const float* __restrict__ bias, bf16* __restrict__ out,
             int H, int W) {
    __shared__ float sIn[8 * 12 * 40];   // 15 KB
    __shared__ float sW[8 * 25 * 32];    // 25 KB
    const int tid = threadIdx.x;
    const int ocg = tid >> 6;     // 0..3 (wave-uniform)
    const int pg  = tid & 63;
    const int pgx = pg & 7;       // 0..7  (x-group of 4)
    const int pgy = pg >> 3;      // 0..7  (row)
    const int xbase = blockIdx.x * 32;
    const int ybase = blockIdx.y * 8;
    const int b = blockIdx.z;
    const bf16* inb = in + (size_t)b * 64 * H * W;

    float acc[4][8];
    #pragma unroll
    for (int px = 0; px < 4; px++)
        #pragma unroll
        for (int oc = 0; oc < 8; oc++) acc[px][oc] = 0.f;

    for (int icc = 0; icc < 64; icc += 8) {
        __syncthreads();
        for (int l = tid; l < 8 * 12 * 36; l += 256) {
            int col = l % 36;
            int r   = l / 36;
            int row = r % 12;
            int ic  = r / 12;
            int gy = ybase - 2 + row;
            int gx = xbase - 2 + col;
            float v = 0.f;
            if ((unsigned)gy < (unsigned)H && (unsigned)gx < (unsigned)W)
                v = b2f(inb[((size_t)(icc + ic) * H + gy) * W + gx]);
            sIn[(ic * 12 + row) * 40 + col] = v;
        }
        const float* wsrc = wt + (size_t)icc * 25 * 32;
        for (int l = tid; l < 8 * 25 * 32; l += 256) sW[l] = wsrc[l];
        __syncthreads();

        #pragma unroll 1
        for (int ic = 0; ic < 8; ic++) {
            #pragma unroll
            for (int ky = 0; ky < 5; ky++) {
                const float* rp = &sIn[(ic * 12 + pgy + ky) * 40 + pgx * 4];
                float4 a0 = *(const float4*)rp;
                float4 a1 = *(const float4*)(rp + 4);
                float in8[8] = {a0.x, a0.y, a0.z, a0.w, a1.x, a1.y, a1.z, a1.w};
                #pragma unroll
                for (int kx = 0; kx < 5; kx++) {
                    const float* wp = &sW[(ic * 25 + ky * 5 + kx) * 32 + ocg * 8];
                    float4 w0 = *(const float4*)wp;
                    float4 w1 = *(const float4*)(wp + 4);
                    float w8[8] = {w0.x, w0.y, w0.z, w0.w, w1.x, w1.y, w1.z, w1.w};
                    #pragma unroll
                    for (int oc = 0; oc < 8; oc++)
                        #pragma unroll
                        for (int px = 0; px < 4; px++)
                            acc[px][oc] = fmaf(in8[px + kx], w8[oc], acc[px][oc]);
                }
            }
        }
    }

    const int y = ybase + pgy;
    if (y < H) {
        #pragma unroll
        for (int oc = 0; oc < 8; oc++) {
            const int oco = ocg * 8 + oc;
            const float bi = bias[oco];
            bf16* op = out + ((size_t)(b * 32 + oco) * H + y) * W;
            #pragma unroll
            for (int px = 0; px < 4; px++) {
                int x = xbase + pgx * 4 + px;
                if (x < W) op[x] = f2b(fmaxf(acc[px][oc] + bi, 0.f));
            }
        }
    }
}

// ---------------------------------------------------------------------------
// conv3: 5x5 SAME, IC=32 -> OC=1, + bias, no relu. bf16 in, fp32 out.
// wt is the raw (1,32,5,5) fp32 weight (used directly from d_in).
// ---------------------------------------------------------------------------
__global__ __launch_bounds__(256, 2)
void conv3_k(const bf16* __restrict__ in, const float* __restrict__ wt,
             const float* __restrict__ bias, float* __restrict__ out,
             int H, int W) {
    __shared__ float sIn[8 * 20 * 72];   // 45 KB
    __shared__ float sW[800];
    const int tid = threadIdx.x;
    const int pgx = tid & 15;
    const int pgy = tid >> 4;
    const int xbase = blockIdx.x * 64;
    const int ybase = blockIdx.y * 16;
    const int b = blockIdx.z;
    const bf16* inb = in + (size_t)b * 32 * H * W;
    for (int l = tid; l < 800; l += 256) sW[l] = wt[l];
    float acc[4] = {0.f, 0.f, 0.f, 0.f};

    for (int icc = 0; icc < 32; icc += 8) {
        __syncthreads();
        for (int l = tid; l < 8 * 20 * 68; l += 256) {
            int col = l % 68;
            int r   = l / 68;
            int row = r % 20;
            int ic  = r / 20;
            int gy = ybase - 2 + row;
            int gx = xbase - 2 + col;
            float v = 0.f;
            if ((unsigned)gy < (unsigned)H && (unsigned)gx < (unsigned)W)
                v = b2f(inb[((size_t)(icc + ic) * H + gy) * W + gx]);
            sIn[(ic * 20 + row) * 72 + col] = v;
        }
        __syncthreads();
        #pragma unroll 1
        for (int ic = 0; ic < 8; ic++) {
            #pragma unroll
            for (int ky = 0; ky < 5; ky++) {
                const float* rp = &sIn[(ic * 20 + pgy + ky) * 72 + pgx * 4];
                float4 a0 = *(const float4*)rp;
                float4 a1 = *(const float4*)(rp + 4);
                float in8[8] = {a0.x, a0.y, a0.z, a0.w, a1.x, a1.y, a1.z, a1.w};
                const float* wr = &sW[(icc + ic) * 25 + ky * 5];
                #pragma unroll
                for (int kx = 0; kx < 5; kx++) {
                    float wv = wr[kx];
                    #pragma unroll
                    for (int px = 0; px < 4; px++)
                        acc[px] = fmaf(in8[px + kx], wv, acc[px]);
                }
            }
        }
    }
    const float bi = bias[0];
    const int y = ybase + pgy;
    if (y < H) {
        float* op = out + ((size_t)b * H + y) * W;
        #pragma unroll
        for (int px = 0; px < 4; px++) {
            int x = xbase + pgx * 4 + px;
            if (x < W) op[x] = acc[px] + bi;
        }
    }
}

// ---------------------------------------------------------------------------
// Weight pre-transform: cw2 (oc,ic,5,5) fp32 -> [ic][tap][oc] fp32.
// ---------------------------------------------------------------------------
__global__ void wtrans2_k(const float* __restrict__ src, float* __restrict__ dst) {
    int i = blockIdx.x * 256 + threadIdx.x;
    if (i >= 32 * 64 * 25) return;
    int oc  = i & 31;
    int r   = i >> 5;
    int tap = r % 25;
    int ic  = r / 25;
    dst[i] = src[((size_t)oc * 64 + ic) * 25 + tap];
}

// ---------------------------------------------------------------------------
extern "C" void kernel_launch(void* const* d_in, const int* in_sizes, int n_in,
                              void* d_out, int out_size, void* d_ws, size_t ws_size,
                              hipStream_t stream) {
    const float* x        = (const float*)d_in[0];
    const float* elev0    = (const float*)d_in[1];
    const float* elev1    = (const float*)d_in[2];
    const int*   psi_idx1 = (const int*)  d_in[3];
    const float* psi_val1 = (const float*)d_in[4];
    const float* w1       = (const float*)d_in[5];
    const float* b1       = (const float*)d_in[6];
    const float* cw2_1    = (const float*)d_in[7];
    const float* cb2_1    = (const float*)d_in[8];
    const float* cw3_1    = (const float*)d_in[9];
    const float* cb3_1    = (const float*)d_in[10];
    const int*   psi_idx2 = (const int*)  d_in[11];
    const float* psi_val2 = (const float*)d_in[12];
    const float* w2       = (const float*)d_in[13];
    const float* b2       = (const float*)d_in[14];
    const float* cw2_2    = (const float*)d_in[15];
    const float* cb2_2    = (const float*)d_in[16];
    const float* cw3_2    = (const float*)d_in[17];
    const float* cb3_2    = (const float*)d_in[18];

    const int B = 4;
    const int H1 = 180, W1 = 360, P1 = H1 * W1;   // stage-1 grid
    const int H2 = 360, W2 = 720, P2 = H2 * W2;   // stage-2 grid

    // workspace layout (bytes)
    char* ws = (char*)d_ws;
    bf16*  h     = (bf16*) (ws);                      // 4*64*P2*2 = 132710400
    bf16*  c     = (bf16*) (ws + 132710400);          // 4*32*P2*2 =  66355200
    float* u1    = (float*)(ws + 199065600);          // 4*P1*4    =   1036800
    float* s1    = (float*)(ws + 200102400);          // 4*P1*4    =   1036800
    float* u2    = (float*)(ws + 201139200);          // 4*P2*4    =   4147200
    float* wt2_1 = (float*)(ws + 205286400);          // 51200*4   =    204800
    float* wt2_2 = (float*)(ws + 205491200);          //                204800
    (void)ws_size; (void)in_sizes; (void)n_in; (void)out_size;

    // weight pre-transforms
    wtrans2_k<<<(32 * 64 * 25 + 255) / 256, 256, 0, stream>>>(cw2_1, wt2_1);
    wtrans2_k<<<(32 * 64 * 25 + 255) / 256, 256, 0, stream>>>(cw2_2, wt2_2);

    // ---- stage 1 ----
    upsample2x_k<<<(B * P1 + 255) / 256, 256, 0, stream>>>(x, u1, B, 90, 180);
    disco_k<<<(P1 + 255) / 256, 256, 0, stream>>>(
        u1, elev0, psi_idx1, psi_val1, w1, b1, h, P1);
    conv2_k<<<dim3((W1 + 31) / 32, (H1 + 7) / 8, B), 256, 0, stream>>>(
        h, wt2_1, cb2_1, c, H1, W1);
    conv3_k<<<dim3((W1 + 63) / 64, (H1 + 15) / 16, B), 256, 0, stream>>>(
        c, cw3_1, cb3_1, s1, H1, W1);

    // ---- stage 2 ----
    upsample2x_k<<<(B * P2 + 255) / 256, 256, 0, stream>>>(s1, u2, B, H1, W1);
    disco_k<<<(P2 + 255) / 256, 256, 0, stream>>>(
        u2, elev1, psi_idx2, psi_val2, w2, b2, h, P2);
    conv2_k<<<dim3((W2 + 31) / 32, (H2 + 7) / 8, B), 256, 0, stream>>>(
        h, wt2_2, cb2_2, c, H2, W2);
    conv3_k<<<dim3((W2 + 63) / 64, (H2 + 15) / 16, B), 256, 0, stream>>>(
        c, cw3_2, cb3_2, (float*)d_out, H2, W2);
}

// Round 3
// 825.565 us; speedup vs baseline: 2.5920x; 2.5920x over previous
//
#include <hip/hip_runtime.h>
#include <hip/hip_bf16.h>

typedef __hip_bfloat16 bf16;
typedef __attribute__((ext_vector_type(8))) short short8;
typedef __attribute__((ext_vector_type(4))) short short4v;
typedef __attribute__((ext_vector_type(4))) float float4v;

__device__ __forceinline__ float b2f(bf16 x) { return __bfloat162float(x); }
__device__ __forceinline__ short f2bs(float x) {
    bf16 b = __float2bfloat16(x);
    return *reinterpret_cast<short*>(&b);
}

// ---------------------------------------------------------------------------
// Bilinear 2x upsample, half-pixel centers, edge clamp. fp32 in/out.
// ---------------------------------------------------------------------------
__global__ void upsample2x_k(const float* __restrict__ in, float* __restrict__ out,
                             int B, int H, int W) {
    const int OH = 2 * H, OW = 2 * W;
    const long total = (long)B * OH * OW;
    long i = (long)blockIdx.x * blockDim.x + threadIdx.x;
    if (i >= total) return;
    int ox = (int)(i % OW);
    long r = i / OW;
    int oy = (int)(r % OH);
    int b  = (int)(r / OH);
    float sy = fminf(fmaxf(oy * 0.5f - 0.25f, 0.0f), (float)(H - 1));
    float sx = fminf(fmaxf(ox * 0.5f - 0.25f, 0.0f), (float)(W - 1));
    int y0 = (int)sy; float ty = sy - (float)y0; int y1 = min(y0 + 1, H - 1);
    int x0 = (int)sx; float tx = sx - (float)x0; int x1 = min(x0 + 1, W - 1);
    const float* p = in + (size_t)b * H * W;
    float v00 = p[(size_t)y0 * W + x0];
    float v01 = p[(size_t)y0 * W + x1];
    float v10 = p[(size_t)y1 * W + x0];
    float v11 = p[(size_t)y1 * W + x1];
    float v = (v00 * (1.f - ty) + v10 * ty) * (1.f - tx)
            + (v01 * (1.f - ty) + v11 * ty) * tx;
    out[i] = v;
}

// ---------------------------------------------------------------------------
// Weight pack for conv2 MFMA B-fragments:
// dst[icc 2][tap 25][nt 2][lane 64][j 8] (bf16 bits), lane=q*16+n:
//   B[k=q*8+j][oc=nt*16+n], ic = icc*32+q*8+j. src cw2 (32 oc, 64 ic, 5,5) fp32.
// ---------------------------------------------------------------------------
__global__ void wpack2_k(const float* __restrict__ src, short* __restrict__ dst) {
    int i = blockIdx.x * 256 + threadIdx.x;
    if (i >= 51200) return;
    int j   = i & 7;
    int r   = i >> 3;
    int lane = r & 63;
    int r2  = r >> 6;
    int nt  = r2 & 1;
    int r3  = r2 >> 1;
    int tap = r3 % 25;
    int icc = r3 / 25;
    int q = lane >> 4, n = lane & 15;
    int oc = nt * 16 + n;
    int ic = icc * 32 + q * 8 + j;
    dst[i] = f2bs(src[((size_t)oc * 64 + ic) * 25 + tap]);
}

// ---------------------------------------------------------------------------
// Weight pack for disco MFMA A-fragments:
// dst[mtile 4][lane 64][j 8], lane=q*16+mm: A[m=oc=mtile*16+mm][k=q*8+j],
// k<18 -> w[oc][k] (w is (64,2,9) fp32, flattened k=c*9+k9), else 0.
// ---------------------------------------------------------------------------
__global__ void wpackD_k(const float* __restrict__ w, short* __restrict__ dst) {
    int i = blockIdx.x * 256 + threadIdx.x;
    if (i >= 2048) return;
    int j = i & 7;
    int r = i >> 3;
    int lane = r & 63;
    int mtile = r >> 6;
    int q = lane >> 4, mm = lane & 15;
    int oc = mtile * 16 + mm;
    int k = q * 8 + j;
    dst[i] = (k < 18) ? f2bs(w[oc * 18 + k]) : (short)0;
}

// ---------------------------------------------------------------------------
// disco conv with MFMA output matmul.
// Phase 1 (per batch): per-thread gather+fma -> z[18] fp32, write bf16 to LDS.
// Phase 2: y[64 oc][256 px] = W(A-frags, regs) x Z(LDS) via 16x16x32 MFMA,
// +bias, relu, store h pixel-major [b][p][64] bf16.
// ---------------------------------------------------------------------------
__global__ __launch_bounds__(256)
void disco_k(const float* __restrict__ ch0, const float* __restrict__ ch1,
             const int* __restrict__ psi_idx, const float* __restrict__ psi_val,
             const short* __restrict__ wfragD, const float* __restrict__ bias,
             short* __restrict__ outh, int P) {
    __shared__ short zs[256 * 40];   // [pixel 256][40-slot pad] bf16 bits, 20.5 KB
    const int tid  = threadIdx.x;
    const int lane = tid & 63;
    const int wv   = tid >> 6;       // wave 0..3
    const int q    = lane >> 4;      // 0..3
    const int n    = lane & 15;

    // zero-init z rows (pad cols stay zero forever)
    for (int c0 = 0; c0 < 40; c0 += 8) *(short8*)(zs + tid * 40 + c0) = (short8)0;

    // resident W A-frags + per-lane bias
    short8 af[4];
    float brg[4][4];
    #pragma unroll
    for (int mt = 0; mt < 4; mt++) {
        af[mt] = *(const short8*)(wfragD + ((mt * 64 + lane) << 3));
        #pragma unroll
        for (int r = 0; r < 4; r++) brg[mt][r] = bias[mt * 16 + q * 4 + r];
    }

    const int p = blockIdx.x * 256 + tid;
    const bool valid = p < P;

    int idx[8];
    float pv[9][8];
    if (valid) {
        const int* ip = psi_idx + (size_t)p * 8;
        int4 ia = *(const int4*)ip;
        int4 ib = *(const int4*)(ip + 4);
        idx[0]=ia.x; idx[1]=ia.y; idx[2]=ia.z; idx[3]=ia.w;
        idx[4]=ib.x; idx[5]=ib.y; idx[6]=ib.z; idx[7]=ib.w;
        #pragma unroll
        for (int k = 0; k < 9; k++) {
            const float* qp = psi_val + ((size_t)k * P + p) * 8;
            float4 qa = *(const float4*)qp;
            float4 qb = *(const float4*)(qp + 4);
            pv[k][0]=qa.x; pv[k][1]=qa.y; pv[k][2]=qa.z; pv[k][3]=qa.w;
            pv[k][4]=qb.x; pv[k][5]=qb.y; pv[k][6]=qb.z; pv[k][7]=qb.w;
        }
    }

    for (int bq = 0; bq < 4; bq++) {
        // ---- phase 1: z ----
        if (valid) {
            const float* c0 = ch0 + (size_t)bq * P;
            const float* c1 = ch1 + (size_t)bq * P;
            float g0[8], g1[8];
            #pragma unroll
            for (int t = 0; t < 8; t++) { g0[t] = c0[idx[t]]; g1[t] = c1[idx[t]]; }
            float z[18];
            #pragma unroll
            for (int j = 0; j < 18; j++) z[j] = 0.f;
            #pragma unroll
            for (int k = 0; k < 9; k++) {
                #pragma unroll
                for (int t = 0; t < 8; t++) {
                    z[k]     = fmaf(g0[t], pv[k][t], z[k]);
                    z[9 + k] = fmaf(g1[t], pv[k][t], z[9 + k]);
                }
            }
            #pragma unroll
            for (int c0i = 0; c0i < 16; c0i += 4) {
                short4v t4;
                t4.x = f2bs(z[c0i]); t4.y = f2bs(z[c0i+1]);
                t4.z = f2bs(z[c0i+2]); t4.w = f2bs(z[c0i+3]);
                *(short4v*)(zs + tid * 40 + c0i) = t4;
            }
            unsigned int lo = (unsigned short)f2bs(z[16]);
            unsigned int hi = (unsigned short)f2bs(z[17]);
            *(unsigned int*)(zs + tid * 40 + 16) = lo | (hi << 16);
        }
        __syncthreads();

        // ---- phase 2: MFMA ----
        #pragma unroll
        for (int t = 0; t < 4; t++) {
            const int nt  = wv * 4 + t;
            const int pix = blockIdx.x * 256 + nt * 16 + n;
            short8 bz = *(const short8*)(zs + (nt * 16 + n) * 40 + q * 8);
            const bool pok = pix < P;
            short* hp = outh + ((size_t)bq * P + pix) * 64;
            #pragma unroll
            for (int mt = 0; mt < 4; mt++) {
                float4v acc = {0.f, 0.f, 0.f, 0.f};
                acc = __builtin_amdgcn_mfma_f32_16x16x32_bf16(af[mt], bz, acc, 0, 0, 0);
                if (pok) {
                    short4v o;
                    o.x = f2bs(fmaxf(acc.x + brg[mt][0], 0.f));
                    o.y = f2bs(fmaxf(acc.y + brg[mt][1], 0.f));
                    o.z = f2bs(fmaxf(acc.z + brg[mt][2], 0.f));
                    o.w = f2bs(fmaxf(acc.w + brg[mt][3], 0.f));
                    *(short4v*)(hp + mt * 16 + q * 4) = o;
                }
            }
        }
        __syncthreads();
    }
}

// ---------------------------------------------------------------------------
// conv2 implicit-GEMM MFMA: 5x5 SAME, IC=64 -> OC=32, bias+relu.
// Input h pixel-major bf16 [b][y*W+x][64]. Output c channel-major bf16.
// Block 256 thr = 4 waves; tile 64x x 4y; wave = 1 row, 4 Mtiles x 2 Ntiles.
// LDS slab [8 rows][68 cols][40-slot pad] bf16 (43.5 KB), ic-chunked by 32.
// B-frags pre-packed in global (L2 broadcast), never touch LDS.
// ---------------------------------------------------------------------------
__global__ __launch_bounds__(256, 2)
void conv2_k(const short* __restrict__ hS, const short* __restrict__ wfrag,
             const float* __restrict__ bias, short* __restrict__ outc,
             int H, int W) {
    __shared__ short slab[8 * 68 * 40];   // 43,520 B
    const int tid  = threadIdx.x;
    const int wv   = tid >> 6;
    const int lane = tid & 63;
    const int q    = lane >> 4;
    const int m    = lane & 15;
    const int xbase = blockIdx.x * 64;
    const int ybase = blockIdx.y * 4;
    const int b     = blockIdx.z;
    const short* hb = hS + (size_t)b * H * W * 64;

    float4v acc[4][2];
    #pragma unroll
    for (int xt = 0; xt < 4; xt++)
        #pragma unroll
        for (int nt = 0; nt < 2; nt++)
            acc[xt][nt] = (float4v){0.f, 0.f, 0.f, 0.f};

    const float bs0 = bias[m];
    const float bs1 = bias[16 + m];
    const int vbase = (wv * 68 + m) * 40 + q * 8;   // per-lane A-frag base (shorts)

    for (int icc = 0; icc < 2; icc++) {
        __syncthreads();
        for (int l = tid; l < 2176; l += 256) {      // 8*68*4 16B-chunks
            int qq  = l & 3;
            int pix = l >> 2;            // row*68+col
            int row = pix / 68;
            int col = pix - row * 68;
            int gy = ybase - 2 + row;
            int gx = xbase - 2 + col;
            short8 v = (short8)0;
            if ((unsigned)gy < (unsigned)H && (unsigned)gx < (unsigned)W)
                v = *(const short8*)(hb + ((size_t)gy * W + gx) * 64 + icc * 32 + qq * 8);
            *(short8*)(slab + pix * 40 + qq * 8) = v;
        }
        __syncthreads();

        const short* wfr = wfrag + (size_t)icc * 25600;
        #pragma unroll
        for (int ky = 0; ky < 5; ky++) {
            #pragma unroll
            for (int kx = 0; kx < 5; kx++) {
                const int tap = ky * 5 + kx;
                short8 wf0 = *(const short8*)(wfr + ((tap * 2 + 0) * 64 + lane) * 8);
                short8 wf1 = *(const short8*)(wfr + ((tap * 2 + 1) * 64 + lane) * 8);
                const int aoff = vbase + (ky * 68 + kx) * 40;
                #pragma unroll
                for (int xt = 0; xt < 4; xt++) {
                    short8 a = *(const short8*)(slab + aoff + xt * 640);
                    acc[xt][0] = __builtin_amdgcn_mfma_f32_16x16x32_bf16(a, wf0, acc[xt][0], 0, 0, 0);
                    acc[xt][1] = __builtin_amdgcn_mfma_f32_16x16x32_bf16(a, wf1, acc[xt][1], 0, 0, 0);
                }
            }
        }
    }

    const int y = ybase + wv;
    #pragma unroll
    for (int xt = 0; xt < 4; xt++) {
        const int x0 = xbase + xt * 16 + q * 4;
        if (x0 < W) {
            #pragma unroll
            for (int nt = 0; nt < 2; nt++) {
                const int oc = nt * 16 + m;
                const float bi = nt ? bs1 : bs0;
                short4v o;
                o.x = f2bs(fmaxf(acc[xt][nt].x + bi, 0.f));
                o.y = f2bs(fmaxf(acc[xt][nt].y + bi, 0.f));
                o.z = f2bs(fmaxf(acc[xt][nt].z + bi, 0.f));
                o.w = f2bs(fmaxf(acc[xt][nt].w + bi, 0.f));
                *(short4v*)(outc + (((size_t)(b * 32 + oc) * H + y) * W + x0)) = o;
            }
        }
    }
}

// ---------------------------------------------------------------------------
// conv3: 5x5 SAME, IC=32 -> OC=1, + bias, no relu. bf16 in, fp32 out.
// (unchanged from round 2 — ~1% of runtime)
// ---------------------------------------------------------------------------
__global__ __launch_bounds__(256, 2)
void conv3_k(const bf16* __restrict__ in, const float* __restrict__ wt,
             const float* __restrict__ bias, float* __restrict__ out,
             int H, int W) {
    __shared__ float sIn[8 * 20 * 72];   // 45 KB
    __shared__ float sW[800];
    const int tid = threadIdx.x;
    const int pgx = tid & 15;
    const int pgy = tid >> 4;
    const int xbase = blockIdx.x * 64;
    const int ybase = blockIdx.y * 16;
    const int b = blockIdx.z;
    const bf16* inb = in + (size_t)b * 32 * H * W;
    for (int l = tid; l < 800; l += 256) sW[l] = wt[l];
    float acc[4] = {0.f, 0.f, 0.f, 0.f};

    for (int icc = 0; icc < 32; icc += 8) {
        __syncthreads();
        for (int l = tid; l < 8 * 20 * 68; l += 256) {
            int col = l % 68;
            int r   = l / 68;
            int row = r % 20;
            int ic  = r / 20;
            int gy = ybase - 2 + row;
            int gx = xbase - 2 + col;
            float v = 0.f;
            if ((unsigned)gy < (unsigned)H && (unsigned)gx < (unsigned)W)
                v = b2f(inb[((size_t)(icc + ic) * H + gy) * W + gx]);
            sIn[(ic * 20 + row) * 72 + col] = v;
        }
        __syncthreads();
        #pragma unroll 1
        for (int ic = 0; ic < 8; ic++) {
            #pragma unroll
            for (int ky = 0; ky < 5; ky++) {
                const float* rp = &sIn[(ic * 20 + pgy + ky) * 72 + pgx * 4];
                float4 a0 = *(const float4*)rp;
                float4 a1 = *(const float4*)(rp + 4);
                float in8[8] = {a0.x, a0.y, a0.z, a0.w, a1.x, a1.y, a1.z, a1.w};
                const float* wr = &sW[(icc + ic) * 25 + ky * 5];
                #pragma unroll
                for (int kx = 0; kx < 5; kx++) {
                    float wvv = wr[kx];
                    #pragma unroll
                    for (int px = 0; px < 4; px++)
                        acc[px] = fmaf(in8[px + kx], wvv, acc[px]);
                }
            }
        }
    }
    const float bi = bias[0];
    const int y = ybase + pgy;
    if (y < H) {
        float* op = out + ((size_t)b * H + y) * W;
        #pragma unroll
        for (int px = 0; px < 4; px++) {
            int x = xbase + pgx * 4 + px;
            if (x < W) op[x] = acc[px] + bi;
        }
    }
}

// ---------------------------------------------------------------------------
extern "C" void kernel_launch(void* const* d_in, const int* in_sizes, int n_in,
                              void* d_out, int out_size, void* d_ws, size_t ws_size,
                              hipStream_t stream) {
    const float* x        = (const float*)d_in[0];
    const float* elev0    = (const float*)d_in[1];
    const float* elev1    = (const float*)d_in[2];
    const int*   psi_idx1 = (const int*)  d_in[3];
    const float* psi_val1 = (const float*)d_in[4];
    const float* w1       = (const float*)d_in[5];
    const float* b1       = (const float*)d_in[6];
    const float* cw2_1    = (const float*)d_in[7];
    const float* cb2_1    = (const float*)d_in[8];
    const float* cw3_1    = (const float*)d_in[9];
    const float* cb3_1    = (const float*)d_in[10];
    const int*   psi_idx2 = (const int*)  d_in[11];
    const float* psi_val2 = (const float*)d_in[12];
    const float* w2       = (const float*)d_in[13];
    const float* b2       = (const float*)d_in[14];
    const float* cw2_2    = (const float*)d_in[15];
    const float* cb2_2    = (const float*)d_in[16];
    const float* cw3_2    = (const float*)d_in[17];
    const float* cb3_2    = (const float*)d_in[18];

    const int B = 4;
    const int H1 = 180, W1 = 360, P1 = H1 * W1;
    const int H2 = 360, W2 = 720, P2 = H2 * W2;

    // workspace layout (bytes)
    char* ws = (char*)d_ws;
    short* h      = (short*)(ws);                    // 4*64*P2*2 = 132,710,400
    bf16*  c      = (bf16*) (ws + 132710400);        // 4*32*P2*2 =  66,355,200
    float* u1     = (float*)(ws + 199065600);        //              1,036,800
    float* s1     = (float*)(ws + 200102400);        //              1,036,800
    float* u2     = (float*)(ws + 201139200);        //              4,147,200
    short* wfA    = (short*)(ws + 205286400);        // conv2_1 B-frags 102,400
    short* wfB    = (short*)(ws + 205388800);        // conv2_2 B-frags 102,400
    short* wfD1   = (short*)(ws + 205491200);        // disco1 A-frags    4,096
    short* wfD2   = (short*)(ws + 205495296);        // disco2 A-frags    4,096
    (void)ws_size; (void)in_sizes; (void)n_in; (void)out_size;

    // weight packs
    wpack2_k<<<(51200 + 255) / 256, 256, 0, stream>>>(cw2_1, wfA);
    wpack2_k<<<(51200 + 255) / 256, 256, 0, stream>>>(cw2_2, wfB);
    wpackD_k<<<8, 256, 0, stream>>>(w1, wfD1);
    wpackD_k<<<8, 256, 0, stream>>>(w2, wfD2);

    // ---- stage 1 ----
    upsample2x_k<<<(B * P1 + 255) / 256, 256, 0, stream>>>(x, u1, B, 90, 180);
    disco_k<<<(P1 + 255) / 256, 256, 0, stream>>>(
        u1, elev0, psi_idx1, psi_val1, wfD1, b1, h, P1);
    conv2_k<<<dim3((W1 + 63) / 64, H1 / 4, B), 256, 0, stream>>>(
        h, wfA, cb2_1, (short*)c, H1, W1);
    conv3_k<<<dim3((W1 + 63) / 64, (H1 + 15) / 16, B), 256, 0, stream>>>(
        c, cw3_1, cb3_1, s1, H1, W1);

    // ---- stage 2 ----
    upsample2x_k<<<(B * P2 + 255) / 256, 256, 0, stream>>>(s1, u2, B, H1, W1);
    disco_k<<<(P2 + 255) / 256, 256, 0, stream>>>(
        u2, elev1, psi_idx2, psi_val2, wfD2, b2, h, P2);
    conv2_k<<<dim3((W2 + 63) / 64, H2 / 4, B), 256, 0, stream>>>(
        h, wfB, cb2_2, (short*)c, H2, W2);
    conv3_k<<<dim3((W2 + 63) / 64, (H2 + 15) / 16, B), 256, 0, stream>>>(
        c, cw3_2, cb3_2, (float*)d_out, H2, W2);
}

// Round 4
// 556.375 us; speedup vs baseline: 3.8460x; 1.4838x over previous
//
#include <hip/hip_runtime.h>
#include <hip/hip_bf16.h>

typedef __hip_bfloat16 bf16;
typedef __attribute__((ext_vector_type(8))) short short8;
typedef __attribute__((ext_vector_type(4))) short short4v;
typedef __attribute__((ext_vector_type(4))) float float4v;

__device__ __forceinline__ short f2bs(float x) {
    bf16 b = __float2bfloat16(x);
    return *reinterpret_cast<short*>(&b);
}

// ---------------------------------------------------------------------------
// Bilinear 2x upsample + pack with elev: out2[i] = {upsampled(i), elev(i)}.
// fp32 in/out. i spans B*(2H)*(2W).
// ---------------------------------------------------------------------------
__global__ void upsample_pack_k(const float* __restrict__ in,
                                const float* __restrict__ elev,
                                float* __restrict__ out2, int B, int H, int W) {
    const int OH = 2 * H, OW = 2 * W;
    const long total = (long)B * OH * OW;
    long i = (long)blockIdx.x * blockDim.x + threadIdx.x;
    if (i >= total) return;
    int ox = (int)(i % OW);
    long r = i / OW;
    int oy = (int)(r % OH);
    int b  = (int)(r / OH);
    float sy = fminf(fmaxf(oy * 0.5f - 0.25f, 0.0f), (float)(H - 1));
    float sx = fminf(fmaxf(ox * 0.5f - 0.25f, 0.0f), (float)(W - 1));
    int y0 = (int)sy; float ty = sy - (float)y0; int y1 = min(y0 + 1, H - 1);
    int x0 = (int)sx; float tx = sx - (float)x0; int x1 = min(x0 + 1, W - 1);
    const float* p = in + (size_t)b * H * W;
    float v00 = p[(size_t)y0 * W + x0];
    float v01 = p[(size_t)y0 * W + x1];
    float v10 = p[(size_t)y1 * W + x0];
    float v11 = p[(size_t)y1 * W + x1];
    float v = (v00 * (1.f - ty) + v10 * ty) * (1.f - tx)
            + (v01 * (1.f - ty) + v11 * ty) * tx;
    float2 o; o.x = v; o.y = elev[i];
    *(float2*)(out2 + i * 2) = o;
}

// ---------------------------------------------------------------------------
// conv2 weight pack as MFMA A-fragments:
// dst[icc 2][tap 25][mt 2][lane 64][j 8]; lane = q*16+m:
//   A[m=oc=mt*16+m][k], k = q*8+j -> ic = icc*32+q*8+j.
// src cw2 (32 oc, 64 ic, 5, 5) fp32.
// ---------------------------------------------------------------------------
__global__ void wpack2_k(const float* __restrict__ src, short* __restrict__ dst) {
    int i = blockIdx.x * 256 + threadIdx.x;
    if (i >= 51200) return;
    int j    = i & 7;
    int r    = i >> 3;
    int lane = r & 63;
    int r2   = r >> 6;
    int mt   = r2 & 1;
    int r3   = r2 >> 1;
    int tap  = r3 % 25;
    int icc  = r3 / 25;
    int m = lane & 15, q = lane >> 4;
    int oc = mt * 16 + m;
    int ic = icc * 32 + q * 8 + j;
    dst[i] = f2bs(src[((size_t)oc * 64 + ic) * 25 + tap]);
}

// ---------------------------------------------------------------------------
// conv3 weight pack as MFMA A-fragments (OC=1, rows m>0 zero):
// dst[tap 25][lane 64][j 8]; lane = q*16+m: A[m][k=ic=q*8+j] = (m==0)?w[ic][tap]:0
// src cw3 (1, 32, 5, 5) fp32.
// ---------------------------------------------------------------------------
__global__ void wpack3_k(const float* __restrict__ src, short* __restrict__ dst) {
    int i = blockIdx.x * 256 + threadIdx.x;
    if (i >= 12800) return;
    int j    = i & 7;
    int r    = i >> 3;
    int lane = r & 63;
    int tap  = r >> 6;
    int m = lane & 15, q = lane >> 4;
    dst[i] = (m == 0) ? f2bs(src[(size_t)(q * 8 + j) * 25 + tap]) : (short)0;
}

// ---------------------------------------------------------------------------
// disco weight pack as MFMA A-fragments:
// dst[mtile 4][lane 64][j 8]; lane=q*16+mm: A[m=oc=mtile*16+mm][k=q*8+j],
// k<18 -> w[oc][k], else 0. w is (64,2,9) fp32 flat.
// ---------------------------------------------------------------------------
__global__ void wpackD_k(const float* __restrict__ w, short* __restrict__ dst) {
    int i = blockIdx.x * 256 + threadIdx.x;
    if (i >= 2048) return;
    int j = i & 7;
    int r = i >> 3;
    int lane = r & 63;
    int mtile = r >> 6;
    int q = lane >> 4, mm = lane & 15;
    int oc = mtile * 16 + mm;
    int k = q * 8 + j;
    dst[i] = (k < 18) ? f2bs(w[oc * 18 + k]) : (short)0;
}

// ---------------------------------------------------------------------------
// disco conv with MFMA output matmul.
// ui: interleaved [b][p][2] fp32 {upsampled, elev}. Per-thread gather (8x
// dwordx2) + fma -> z[18] fp32 -> bf16 LDS. Then y[64][256px] via 16x16x32
// MFMA (W A-frags resident in regs), +bias, relu, h pixel-major [b][p][64].
// ---------------------------------------------------------------------------
__global__ __launch_bounds__(256)
void disco_k(const float* __restrict__ ui,
             const int* __restrict__ psi_idx, const float* __restrict__ psi_val,
             const short* __restrict__ wfragD, const float* __restrict__ bias,
             short* __restrict__ outh, int P) {
    __shared__ short zs[256 * 40];   // [pixel 256][40-slot pad], 20.5 KB
    const int tid  = threadIdx.x;
    const int lane = tid & 63;
    const int wv   = tid >> 6;
    const int q    = lane >> 4;
    const int n    = lane & 15;

    for (int c0 = 0; c0 < 40; c0 += 8) *(short8*)(zs + tid * 40 + c0) = (short8)0;

    short8 af[4];
    float brg[4][4];
    #pragma unroll
    for (int mt = 0; mt < 4; mt++) {
        af[mt] = *(const short8*)(wfragD + ((mt * 64 + lane) << 3));
        #pragma unroll
        for (int r = 0; r < 4; r++) brg[mt][r] = bias[mt * 16 + q * 4 + r];
    }

    const int p = blockIdx.x * 256 + tid;
    const bool valid = p < P;

    int idx[8];
    float pv[9][8];
    if (valid) {
        const int* ip = psi_idx + (size_t)p * 8;
        int4 ia = *(const int4*)ip;
        int4 ib = *(const int4*)(ip + 4);
        idx[0]=ia.x; idx[1]=ia.y; idx[2]=ia.z; idx[3]=ia.w;
        idx[4]=ib.x; idx[5]=ib.y; idx[6]=ib.z; idx[7]=ib.w;
        #pragma unroll
        for (int k = 0; k < 9; k++) {
            const float* qp = psi_val + ((size_t)k * P + p) * 8;
            float4 qa = *(const float4*)qp;
            float4 qb = *(const float4*)(qp + 4);
            pv[k][0]=qa.x; pv[k][1]=qa.y; pv[k][2]=qa.z; pv[k][3]=qa.w;
            pv[k][4]=qb.x; pv[k][5]=qb.y; pv[k][6]=qb.z; pv[k][7]=qb.w;
        }
    }

    for (int bq = 0; bq < 4; bq++) {
        if (valid) {
            const float* ub = ui + (size_t)bq * P * 2;
            float g0[8], g1[8];
            #pragma unroll
            for (int t = 0; t < 8; t++) {
                float2 g = *(const float2*)(ub + (size_t)idx[t] * 2);
                g0[t] = g.x; g1[t] = g.y;
            }
            float z[18];
            #pragma unroll
            for (int j = 0; j < 18; j++) z[j] = 0.f;
            #pragma unroll
            for (int k = 0; k < 9; k++) {
                #pragma unroll
                for (int t = 0; t < 8; t++) {
                    z[k]     = fmaf(g0[t], pv[k][t], z[k]);
                    z[9 + k] = fmaf(g1[t], pv[k][t], z[9 + k]);
                }
            }
            #pragma unroll
            for (int c0i = 0; c0i < 16; c0i += 4) {
                short4v t4;
                t4.x = f2bs(z[c0i]); t4.y = f2bs(z[c0i+1]);
                t4.z = f2bs(z[c0i+2]); t4.w = f2bs(z[c0i+3]);
                *(short4v*)(zs + tid * 40 + c0i) = t4;
            }
            unsigned int lo = (unsigned short)f2bs(z[16]);
            unsigned int hi = (unsigned short)f2bs(z[17]);
            *(unsigned int*)(zs + tid * 40 + 16) = lo | (hi << 16);
        }
        __syncthreads();

        #pragma unroll
        for (int t = 0; t < 4; t++) {
            const int nt  = wv * 4 + t;
            const int pix = blockIdx.x * 256 + nt * 16 + n;
            short8 bz = *(const short8*)(zs + (nt * 16 + n) * 40 + q * 8);
            const bool pok = pix < P;
            short* hp = outh + ((size_t)bq * P + pix) * 64;
            #pragma unroll
            for (int mt = 0; mt < 4; mt++) {
                float4v acc = {0.f, 0.f, 0.f, 0.f};
                acc = __builtin_amdgcn_mfma_f32_16x16x32_bf16(af[mt], bz, acc, 0, 0, 0);
                if (pok) {
                    short4v o;
                    o.x = f2bs(fmaxf(acc.x + brg[mt][0], 0.f));
                    o.y = f2bs(fmaxf(acc.y + brg[mt][1], 0.f));
                    o.z = f2bs(fmaxf(acc.z + brg[mt][2], 0.f));
                    o.w = f2bs(fmaxf(acc.w + brg[mt][3], 0.f));
                    *(short4v*)(hp + mt * 16 + q * 4) = o;
                }
            }
        }
        __syncthreads();
    }
}

// ---------------------------------------------------------------------------
// conv2 implicit-GEMM MFMA: 5x5 SAME, IC=64 -> OC=32, bias+relu.
// A = weights (global A-frags), B = pixels (LDS slab). Output c PIXEL-MAJOR
// bf16 [b][y*W+x][32]. Block 256 = 4 waves; tile 64x x 4y; wave = 1 row,
// 4 Ntiles(px) x 2 Mtiles(oc). Slab [8 rows][68 cols][40-slot] bf16, 43.5 KB.
// ---------------------------------------------------------------------------
__global__ __launch_bounds__(256, 2)
void conv2_k(const short* __restrict__ hS, const short* __restrict__ wfrag,
             const float* __restrict__ bias, short* __restrict__ outc,
             int H, int W) {
    __shared__ short slab[8 * 68 * 40];   // 43,520 B
    const int tid  = threadIdx.x;
    const int wv   = tid >> 6;
    const int lane = tid & 63;
    const int q    = lane >> 4;
    const int n    = lane & 15;
    const int xbase = blockIdx.x * 64;
    const int ybase = blockIdx.y * 4;
    const int b     = blockIdx.z;
    const short* hb = hS + (size_t)b * H * W * 64;

    float4v acc[4][2];
    #pragma unroll
    for (int nt = 0; nt < 4; nt++)
        #pragma unroll
        for (int mt = 0; mt < 2; mt++)
            acc[nt][mt] = (float4v){0.f, 0.f, 0.f, 0.f};

    float brg[2][4];
    #pragma unroll
    for (int mt = 0; mt < 2; mt++)
        #pragma unroll
        for (int r = 0; r < 4; r++) brg[mt][r] = bias[mt * 16 + q * 4 + r];

    for (int icc = 0; icc < 2; icc++) {
        __syncthreads();
        for (int l = tid; l < 2176; l += 256) {      // 8*68*4 16B-chunks
            int qq  = l & 3;
            int pix = l >> 2;            // row*68+col
            int row = pix / 68;
            int col = pix - row * 68;
            int gy = ybase - 2 + row;
            int gx = xbase - 2 + col;
            short8 v = (short8)0;
            if ((unsigned)gy < (unsigned)H && (unsigned)gx < (unsigned)W)
                v = *(const short8*)(hb + ((size_t)gy * W + gx) * 64 + icc * 32 + qq * 8);
            *(short8*)(slab + pix * 40 + qq * 8) = v;
        }
        __syncthreads();

        const short* wfr = wfrag + (size_t)icc * 25600;
        #pragma unroll
        for (int ky = 0; ky < 5; ky++) {
            #pragma unroll
            for (int kx = 0; kx < 5; kx++) {
                const int tap = ky * 5 + kx;
                short8 wf0 = *(const short8*)(wfr + ((tap * 2 + 0) * 64 + lane) * 8);
                short8 wf1 = *(const short8*)(wfr + ((tap * 2 + 1) * 64 + lane) * 8);
                const int boff = ((wv + ky) * 68 + n + kx) * 40 + q * 8;
                #pragma unroll
                for (int nt = 0; nt < 4; nt++) {
                    short8 bfr = *(const short8*)(slab + boff + nt * 640);
                    acc[nt][0] = __builtin_amdgcn_mfma_f32_16x16x32_bf16(wf0, bfr, acc[nt][0], 0, 0, 0);
                    acc[nt][1] = __builtin_amdgcn_mfma_f32_16x16x32_bf16(wf1, bfr, acc[nt][1], 0, 0, 0);
                }
            }
        }
    }

    const int y = ybase + wv;
    #pragma unroll
    for (int nt = 0; nt < 4; nt++) {
        const int x = xbase + nt * 16 + n;
        if (x < W) {
            short* cp = outc + (((size_t)b * H * W + (size_t)y * W + x) * 32);
            #pragma unroll
            for (int mt = 0; mt < 2; mt++) {
                short4v o;
                o.x = f2bs(fmaxf(acc[nt][mt].x + brg[mt][0], 0.f));
                o.y = f2bs(fmaxf(acc[nt][mt].y + brg[mt][1], 0.f));
                o.z = f2bs(fmaxf(acc[nt][mt].z + brg[mt][2], 0.f));
                o.w = f2bs(fmaxf(acc[nt][mt].w + brg[mt][3], 0.f));
                *(short4v*)(cp + mt * 16 + q * 4) = o;
            }
        }
    }
}

// ---------------------------------------------------------------------------
// conv3 implicit-GEMM MFMA: 5x5 SAME, IC=32 -> OC=1 (M padded to 16), +bias.
// Input c pixel-major bf16 [b][p][32]; output fp32 [b][H][W].
// Block 256 = 4 waves; tile 64x x 4y; wave = 1 row, 4 Ntiles.
// Slab [8 rows][68 cols][40-slot] bf16 (ic in slots 0..31), 43.5 KB.
// ---------------------------------------------------------------------------
__global__ __launch_bounds__(256, 2)
void conv3_k(const short* __restrict__ cP, const short* __restrict__ wf3,
             const float* __restrict__ bias, float* __restrict__ out,
             int H, int W) {
    __shared__ short slab[8 * 68 * 40];   // 43,520 B
    const int tid  = threadIdx.x;
    const int wv   = tid >> 6;
    const int lane = tid & 63;
    const int q    = lane >> 4;
    const int n    = lane & 15;
    const int xbase = blockIdx.x * 64;
    const int ybase = blockIdx.y * 4;
    const int b     = blockIdx.z;
    const short* cb = cP + (size_t)b * H * W * 32;

    for (int l = tid; l < 2176; l += 256) {          // 8*68*4 16B-chunks
        int qq  = l & 3;
        int pix = l >> 2;
        int row = pix / 68;
        int col = pix - row * 68;
        int gy = ybase - 2 + row;
        int gx = xbase - 2 + col;
        short8 v = (short8)0;
        if ((unsigned)gy < (unsigned)H && (unsigned)gx < (unsigned)W)
            v = *(const short8*)(cb + ((size_t)gy * W + gx) * 32 + qq * 8);
        *(short8*)(slab + pix * 40 + qq * 8) = v;
    }
    __syncthreads();

    float4v acc[4];
    #pragma unroll
    for (int nt = 0; nt < 4; nt++) acc[nt] = (float4v){0.f, 0.f, 0.f, 0.f};

    #pragma unroll
    for (int ky = 0; ky < 5; ky++) {
        #pragma unroll
        for (int kx = 0; kx < 5; kx++) {
            const int tap = ky * 5 + kx;
            short8 a = *(const short8*)(wf3 + ((size_t)(tap * 64 + lane)) * 8);
            const int boff = ((wv + ky) * 68 + n + kx) * 40 + q * 8;
            #pragma unroll
            for (int nt = 0; nt < 4; nt++) {
                short8 bfr = *(const short8*)(slab + boff + nt * 640);
                acc[nt] = __builtin_amdgcn_mfma_f32_16x16x32_bf16(a, bfr, acc[nt], 0, 0, 0);
            }
        }
    }

    const int y = ybase + wv;
    const float bi = bias[0];
    if (q == 0 && y < H) {            // D row m=0 lives in lanes 0..15, reg .x
        #pragma unroll
        for (int nt = 0; nt < 4; nt++) {
            const int x = xbase + nt * 16 + n;
            if (x < W) out[((size_t)b * H + y) * W + x] = acc[nt].x + bi;
        }
    }
}

// ---------------------------------------------------------------------------
extern "C" void kernel_launch(void* const* d_in, const int* in_sizes, int n_in,
                              void* d_out, int out_size, void* d_ws, size_t ws_size,
                              hipStream_t stream) {
    const float* x        = (const float*)d_in[0];
    const float* elev0    = (const float*)d_in[1];
    const float* elev1    = (const float*)d_in[2];
    const int*   psi_idx1 = (const int*)  d_in[3];
    const float* psi_val1 = (const float*)d_in[4];
    const float* w1       = (const float*)d_in[5];
    const float* b1       = (const float*)d_in[6];
    const float* cw2_1    = (const float*)d_in[7];
    const float* cb2_1    = (const float*)d_in[8];
    const float* cw3_1    = (const float*)d_in[9];
    const float* cb3_1    = (const float*)d_in[10];
    const int*   psi_idx2 = (const int*)  d_in[11];
    const float* psi_val2 = (const float*)d_in[12];
    const float* w2       = (const float*)d_in[13];
    const float* b2       = (const float*)d_in[14];
    const float* cw2_2    = (const float*)d_in[15];
    const float* cb2_2    = (const float*)d_in[16];
    const float* cw3_2    = (const float*)d_in[17];
    const float* cb3_2    = (const float*)d_in[18];

    const int B = 4;
    const int H1 = 180, W1 = 360, P1 = H1 * W1;
    const int H2 = 360, W2 = 720, P2 = H2 * W2;

    // workspace layout (bytes); u2i overlaps the tail of c (stage-1 c uses
    // only the first 16.6 MB; u2i is dead before conv2_2 rewrites c).
    char* ws = (char*)d_ws;
    short* h    = (short*)(ws);                      // 132,710,400
    short* c    = (short*)(ws + 132710400);          //  66,355,200 -> 199,065,600
    float* u2i  = (float*)(ws + 149299200);          //   8,294,400 (inside c tail)
    float* u1i  = (float*)(ws + 199065600);          //   2,073,600 -> 201,139,200
    float* s1   = (float*)(ws + 201139200);          //   1,036,800 -> 202,176,000
    short* wfA  = (short*)(ws + 202176000);          //     102,400
    short* wfB  = (short*)(ws + 202278400);          //     102,400
    short* wfD1 = (short*)(ws + 202380800);          //       4,096
    short* wfD2 = (short*)(ws + 202384896);          //       4,096
    short* wf31 = (short*)(ws + 202388992);          //      25,600
    short* wf32 = (short*)(ws + 202414592);          //      25,600 -> 202,440,192
    (void)ws_size; (void)in_sizes; (void)n_in; (void)out_size;

    // weight packs
    wpack2_k<<<(51200 + 255) / 256, 256, 0, stream>>>(cw2_1, wfA);
    wpack2_k<<<(51200 + 255) / 256, 256, 0, stream>>>(cw2_2, wfB);
    wpack3_k<<<(12800 + 255) / 256, 256, 0, stream>>>(cw3_1, wf31);
    wpack3_k<<<(12800 + 255) / 256, 256, 0, stream>>>(cw3_2, wf32);
    wpackD_k<<<8, 256, 0, stream>>>(w1, wfD1);
    wpackD_k<<<8, 256, 0, stream>>>(w2, wfD2);

    // ---- stage 1 ----
    upsample_pack_k<<<(B * P1 + 255) / 256, 256, 0, stream>>>(x, elev0, u1i, B, 90, 180);
    disco_k<<<(P1 + 255) / 256, 256, 0, stream>>>(
        u1i, psi_idx1, psi_val1, wfD1, b1, h, P1);
    conv2_k<<<dim3((W1 + 63) / 64, H1 / 4, B), 256, 0, stream>>>(
        h, wfA, cb2_1, c, H1, W1);
    conv3_k<<<dim3((W1 + 63) / 64, H1 / 4, B), 256, 0, stream>>>(
        c, wf31, cb3_1, s1, H1, W1);

    // ---- stage 2 ----
    upsample_pack_k<<<(B * P2 + 255) / 256, 256, 0, stream>>>(s1, elev1, u2i, B, H1, W1);
    disco_k<<<(P2 + 255) / 256, 256, 0, stream>>>(
        u2i, psi_idx2, psi_val2, wfD2, b2, h, P2);
    conv2_k<<<dim3((W2 + 63) / 64, H2 / 4, B), 256, 0, stream>>>(
        h, wfB, cb2_2, c, H2, W2);
    conv3_k<<<dim3((W2 + 63) / 64, H2 / 4, B), 256, 0, stream>>>(
        c, wf32, cb3_2, (float*)d_out, H2, W2);
}

// Round 5
// 542.929 us; speedup vs baseline: 3.9413x; 1.0248x over previous
//
#include <hip/hip_runtime.h>
#include <hip/hip_bf16.h>

typedef __hip_bfloat16 bf16;
typedef __attribute__((ext_vector_type(8))) short short8;
typedef __attribute__((ext_vector_type(4))) short short4v;
typedef __attribute__((ext_vector_type(4))) float float4v;

__device__ __forceinline__ short f2bs(float x) {
    bf16 b = __float2bfloat16(x);
    return *reinterpret_cast<short*>(&b);
}

// ---------------------------------------------------------------------------
// Bilinear 2x upsample + pack with elev: out2[i] = {upsampled(i), elev(i)}.
// ---------------------------------------------------------------------------
__global__ void upsample_pack_k(const float* __restrict__ in,
                                const float* __restrict__ elev,
                                float* __restrict__ out2, int B, int H, int W) {
    const int OH = 2 * H, OW = 2 * W;
    const long total = (long)B * OH * OW;
    long i = (long)blockIdx.x * blockDim.x + threadIdx.x;
    if (i >= total) return;
    int ox = (int)(i % OW);
    long r = i / OW;
    int oy = (int)(r % OH);
    int b  = (int)(r / OH);
    float sy = fminf(fmaxf(oy * 0.5f - 0.25f, 0.0f), (float)(H - 1));
    float sx = fminf(fmaxf(ox * 0.5f - 0.25f, 0.0f), (float)(W - 1));
    int y0 = (int)sy; float ty = sy - (float)y0; int y1 = min(y0 + 1, H - 1);
    int x0 = (int)sx; float tx = sx - (float)x0; int x1 = min(x0 + 1, W - 1);
    const float* p = in + (size_t)b * H * W;
    float v00 = p[(size_t)y0 * W + x0];
    float v01 = p[(size_t)y0 * W + x1];
    float v10 = p[(size_t)y1 * W + x0];
    float v11 = p[(size_t)y1 * W + x1];
    float v = (v00 * (1.f - ty) + v10 * ty) * (1.f - tx)
            + (v01 * (1.f - ty) + v11 * ty) * tx;
    float2 o; o.x = v; o.y = elev[i];
    *(float2*)(out2 + i * 2) = o;
}

// ---------------------------------------------------------------------------
// Fused weight packs (all six arrays in one launch).
// wpack2: dst[icc 2][tap 25][mt 2][lane 64][j 8]; A[m=oc=mt*16+(lane&15)]
//         [k=(lane>>4)*8+j] with ic = icc*32+k. src (32,64,5,5) fp32.
// wpack3: dst[tap 25][lane 64][j 8]; A[m][ic=(lane>>4)*8+j], m==0 else 0.
// wpackD: dst[mt 4][lane 64][j 8]; A[oc=mt*16+(lane&15)][k=(lane>>4)*8+j],
//         k<18 -> w[oc][k] else 0.
// ---------------------------------------------------------------------------
__global__ void packall_k(const float* __restrict__ cw2_1, const float* __restrict__ cw2_2,
                          const float* __restrict__ cw3_1, const float* __restrict__ cw3_2,
                          const float* __restrict__ w1,    const float* __restrict__ w2,
                          short* __restrict__ wfA,  short* __restrict__ wfB,
                          short* __restrict__ wf31, short* __restrict__ wf32,
                          short* __restrict__ wfD1, short* __restrict__ wfD2) {
    int gi = blockIdx.x * 256 + threadIdx.x;
    if (gi < 102400) {
        const float* src = (gi < 51200) ? cw2_1 : cw2_2;
        short* dst       = (gi < 51200) ? wfA   : wfB;
        int i = (gi < 51200) ? gi : gi - 51200;
        int j    = i & 7;
        int r    = i >> 3;
        int lane = r & 63;
        int r2   = r >> 6;
        int mt   = r2 & 1;
        int r3   = r2 >> 1;
        int tap  = r3 % 25;
        int icc  = r3 / 25;
        int m = lane & 15, q = lane >> 4;
        int oc = mt * 16 + m;
        int ic = icc * 32 + q * 8 + j;
        dst[i] = f2bs(src[((size_t)oc * 64 + ic) * 25 + tap]);
    } else if (gi < 128000) {
        int gi2 = gi - 102400;
        const float* src = (gi2 < 12800) ? cw3_1 : cw3_2;
        short* dst       = (gi2 < 12800) ? wf31  : wf32;
        int i = (gi2 < 12800) ? gi2 : gi2 - 12800;
        int j    = i & 7;
        int r    = i >> 3;
        int lane = r & 63;
        int tap  = r >> 6;
        int m = lane & 15, q = lane >> 4;
        dst[i] = (m == 0) ? f2bs(src[(size_t)(q * 8 + j) * 25 + tap]) : (short)0;
    } else if (gi < 132096) {
        int gi2 = gi - 128000;
        const float* src = (gi2 < 2048) ? w1 : w2;
        short* dst       = (gi2 < 2048) ? wfD1 : wfD2;
        int i = (gi2 < 2048) ? gi2 : gi2 - 2048;
        int j = i & 7;
        int r = i >> 3;
        int lane = r & 63;
        int mtile = r >> 6;
        int q = lane >> 4, mm = lane & 15;
        int oc = mtile * 16 + mm;
        int k = q * 8 + j;
        dst[i] = (k < 18) ? f2bs(src[oc * 18 + k]) : (short)0;
    }
}

// ---------------------------------------------------------------------------
// disco conv with MFMA output matmul (unchanged from round 4).
// ---------------------------------------------------------------------------
__global__ __launch_bounds__(256)
void disco_k(const float* __restrict__ ui,
             const int* __restrict__ psi_idx, const float* __restrict__ psi_val,
             const short* __restrict__ wfragD, const float* __restrict__ bias,
             short* __restrict__ outh, int P) {
    __shared__ short zs[256 * 40];
    const int tid  = threadIdx.x;
    const int lane = tid & 63;
    const int wv   = tid >> 6;
    const int q    = lane >> 4;
    const int n    = lane & 15;

    for (int c0 = 0; c0 < 40; c0 += 8) *(short8*)(zs + tid * 40 + c0) = (short8)0;

    short8 af[4];
    float brg[4][4];
    #pragma unroll
    for (int mt = 0; mt < 4; mt++) {
        af[mt] = *(const short8*)(wfragD + ((mt * 64 + lane) << 3));
        #pragma unroll
        for (int r = 0; r < 4; r++) brg[mt][r] = bias[mt * 16 + q * 4 + r];
    }

    const int p = blockIdx.x * 256 + tid;
    const bool valid = p < P;

    int idx[8];
    float pv[9][8];
    if (valid) {
        const int* ip = psi_idx + (size_t)p * 8;
        int4 ia = *(const int4*)ip;
        int4 ib = *(const int4*)(ip + 4);
        idx[0]=ia.x; idx[1]=ia.y; idx[2]=ia.z; idx[3]=ia.w;
        idx[4]=ib.x; idx[5]=ib.y; idx[6]=ib.z; idx[7]=ib.w;
        #pragma unroll
        for (int k = 0; k < 9; k++) {
            const float* qp = psi_val + ((size_t)k * P + p) * 8;
            float4 qa = *(const float4*)qp;
            float4 qb = *(const float4*)(qp + 4);
            pv[k][0]=qa.x; pv[k][1]=qa.y; pv[k][2]=qa.z; pv[k][3]=qa.w;
            pv[k][4]=qb.x; pv[k][5]=qb.y; pv[k][6]=qb.z; pv[k][7]=qb.w;
        }
    }

    for (int bq = 0; bq < 4; bq++) {
        if (valid) {
            const float* ub = ui + (size_t)bq * P * 2;
            float g0[8], g1[8];
            #pragma unroll
            for (int t = 0; t < 8; t++) {
                float2 g = *(const float2*)(ub + (size_t)idx[t] * 2);
                g0[t] = g.x; g1[t] = g.y;
            }
            float z[18];
            #pragma unroll
            for (int j = 0; j < 18; j++) z[j] = 0.f;
            #pragma unroll
            for (int k = 0; k < 9; k++) {
                #pragma unroll
                for (int t = 0; t < 8; t++) {
                    z[k]     = fmaf(g0[t], pv[k][t], z[k]);
                    z[9 + k] = fmaf(g1[t], pv[k][t], z[9 + k]);
                }
            }
            #pragma unroll
            for (int c0i = 0; c0i < 16; c0i += 4) {
                short4v t4;
                t4.x = f2bs(z[c0i]); t4.y = f2bs(z[c0i+1]);
                t4.z = f2bs(z[c0i+2]); t4.w = f2bs(z[c0i+3]);
                *(short4v*)(zs + tid * 40 + c0i) = t4;
            }
            unsigned int lo = (unsigned short)f2bs(z[16]);
            unsigned int hi = (unsigned short)f2bs(z[17]);
            *(unsigned int*)(zs + tid * 40 + 16) = lo | (hi << 16);
        }
        __syncthreads();

        #pragma unroll
        for (int t = 0; t < 4; t++) {
            const int nt  = wv * 4 + t;
            const int pix = blockIdx.x * 256 + nt * 16 + n;
            short8 bz = *(const short8*)(zs + (nt * 16 + n) * 40 + q * 8);
            const bool pok = pix < P;
            short* hp = outh + ((size_t)bq * P + pix) * 64;
            #pragma unroll
            for (int mt = 0; mt < 4; mt++) {
                float4v acc = {0.f, 0.f, 0.f, 0.f};
                acc = __builtin_amdgcn_mfma_f32_16x16x32_bf16(af[mt], bz, acc, 0, 0, 0);
                if (pok) {
                    short4v o;
                    o.x = f2bs(fmaxf(acc.x + brg[mt][0], 0.f));
                    o.y = f2bs(fmaxf(acc.y + brg[mt][1], 0.f));
                    o.z = f2bs(fmaxf(acc.z + brg[mt][2], 0.f));
                    o.w = f2bs(fmaxf(acc.w + brg[mt][3], 0.f));
                    *(short4v*)(hp + mt * 16 + q * 4) = o;
                }
            }
        }
        __syncthreads();
    }
}

// ---------------------------------------------------------------------------
// conv2 implicit-GEMM MFMA, 2 output rows per wave: 5x5 SAME, IC=64->OC=32,
// bias+relu. Tile 64x x 8y; slab [12 rows][68 cols][40-slot] bf16 = 65,280 B.
// B-frag(slab row s) feeds row0 with ky=s and row1 with ky=s-1: LDS reads
// per MFMA drop 0.5 -> 0.3. Output c pixel-major [b][p][32].
// ---------------------------------------------------------------------------
__global__ __launch_bounds__(256, 2)
void conv2_k(const short* __restrict__ hS, const short* __restrict__ wfrag,
             const float* __restrict__ bias, short* __restrict__ outc,
             int H, int W) {
    __shared__ short slab[12 * 68 * 40];   // 65,280 B
    const int tid  = threadIdx.x;
    const int wv   = tid >> 6;
    const int lane = tid & 63;
    const int q    = lane >> 4;
    const int n    = lane & 15;
    const int xbase = blockIdx.x * 64;
    const int ybase = blockIdx.y * 8;
    const int b     = blockIdx.z;
    const short* hb = hS + (size_t)b * H * W * 64;

    float4v acc[2][4][2];   // [row][nt][mt]
    #pragma unroll
    for (int ri = 0; ri < 2; ri++)
        #pragma unroll
        for (int nt = 0; nt < 4; nt++)
            #pragma unroll
            for (int mt = 0; mt < 2; mt++)
                acc[ri][nt][mt] = (float4v){0.f, 0.f, 0.f, 0.f};

    float brg[2][4];
    #pragma unroll
    for (int mt = 0; mt < 2; mt++)
        #pragma unroll
        for (int r = 0; r < 4; r++) brg[mt][r] = bias[mt * 16 + q * 4 + r];

    for (int icc = 0; icc < 2; icc++) {
        __syncthreads();
        for (int l = tid; l < 3264; l += 256) {      // 12*68*4 16B-chunks
            int qq  = l & 3;
            int pix = l >> 2;            // row*68+col
            int row = pix / 68;
            int col = pix - row * 68;
            int gy = ybase - 2 + row;
            int gx = xbase - 2 + col;
            short8 v = (short8)0;
            if ((unsigned)gy < (unsigned)H && (unsigned)gx < (unsigned)W)
                v = *(const short8*)(hb + ((size_t)gy * W + gx) * 64 + icc * 32 + qq * 8);
            *(short8*)(slab + pix * 40 + qq * 8) = v;
        }
        __syncthreads();

        const short* wfr = wfrag + (size_t)icc * 25600;
        #pragma unroll
        for (int t = 0; t < 6; t++) {                // slab row = wv*2 + t
            const int srow = wv * 2 + t;
            #pragma unroll
            for (int kx = 0; kx < 5; kx++) {
                short8 w0a, w0b, w1a, w1b;
                if (t <= 4) {                        // row0 tap (ky=t, kx)
                    const int tp = t * 5 + kx;
                    w0a = *(const short8*)(wfr + ((tp * 2 + 0) * 64 + lane) * 8);
                    w0b = *(const short8*)(wfr + ((tp * 2 + 1) * 64 + lane) * 8);
                }
                if (t >= 1) {                        // row1 tap (ky=t-1, kx)
                    const int tp = (t - 1) * 5 + kx;
                    w1a = *(const short8*)(wfr + ((tp * 2 + 0) * 64 + lane) * 8);
                    w1b = *(const short8*)(wfr + ((tp * 2 + 1) * 64 + lane) * 8);
                }
                const int boff = (srow * 68 + n + kx) * 40 + q * 8;
                #pragma unroll
                for (int nt = 0; nt < 4; nt++) {
                    short8 bfr = *(const short8*)(slab + boff + nt * 640);
                    if (t <= 4) {
                        acc[0][nt][0] = __builtin_amdgcn_mfma_f32_16x16x32_bf16(w0a, bfr, acc[0][nt][0], 0, 0, 0);
                        acc[0][nt][1] = __builtin_amdgcn_mfma_f32_16x16x32_bf16(w0b, bfr, acc[0][nt][1], 0, 0, 0);
                    }
                    if (t >= 1) {
                        acc[1][nt][0] = __builtin_amdgcn_mfma_f32_16x16x32_bf16(w1a, bfr, acc[1][nt][0], 0, 0, 0);
                        acc[1][nt][1] = __builtin_amdgcn_mfma_f32_16x16x32_bf16(w1b, bfr, acc[1][nt][1], 0, 0, 0);
                    }
                }
            }
        }
    }

    #pragma unroll
    for (int ri = 0; ri < 2; ri++) {
        const int y = ybase + wv * 2 + ri;
        if (y < H) {
            #pragma unroll
            for (int nt = 0; nt < 4; nt++) {
                const int x = xbase + nt * 16 + n;
                if (x < W) {
                    short* cp = outc + (((size_t)b * H * W + (size_t)y * W + x) * 32);
                    #pragma unroll
                    for (int mt = 0; mt < 2; mt++) {
                        short4v o;
                        o.x = f2bs(fmaxf(acc[ri][nt][mt].x + brg[mt][0], 0.f));
                        o.y = f2bs(fmaxf(acc[ri][nt][mt].y + brg[mt][1], 0.f));
                        o.z = f2bs(fmaxf(acc[ri][nt][mt].z + brg[mt][2], 0.f));
                        o.w = f2bs(fmaxf(acc[ri][nt][mt].w + brg[mt][3], 0.f));
                        *(short4v*)(cp + mt * 16 + q * 4) = o;
                    }
                }
            }
        }
    }
}

// ---------------------------------------------------------------------------
// conv3 implicit-GEMM MFMA, 2 output rows per wave: 5x5 SAME, IC=32 -> OC=1
// (M padded to 16), +bias. Input c pixel-major [b][p][32]; output fp32.
// Tile 64x x 8y; slab [12][68][40] = 65,280 B.
// ---------------------------------------------------------------------------
__global__ __launch_bounds__(256, 2)
void conv3_k(const short* __restrict__ cP, const short* __restrict__ wf3,
             const float* __restrict__ bias, float* __restrict__ out,
             int H, int W) {
    __shared__ short slab[12 * 68 * 40];
    const int tid  = threadIdx.x;
    const int wv   = tid >> 6;
    const int lane = tid & 63;
    const int q    = lane >> 4;
    const int n    = lane & 15;
    const int xbase = blockIdx.x * 64;
    const int ybase = blockIdx.y * 8;
    const int b     = blockIdx.z;
    const short* cb = cP + (size_t)b * H * W * 32;

    for (int l = tid; l < 3264; l += 256) {
        int qq  = l & 3;
        int pix = l >> 2;
        int row = pix / 68;
        int col = pix - row * 68;
        int gy = ybase - 2 + row;
        int gx = xbase - 2 + col;
        short8 v = (short8)0;
        if ((unsigned)gy < (unsigned)H && (unsigned)gx < (unsigned)W)
            v = *(const short8*)(cb + ((size_t)gy * W + gx) * 32 + qq * 8);
        *(short8*)(slab + pix * 40 + qq * 8) = v;
    }
    __syncthreads();

    float4v acc[2][4];
    #pragma unroll
    for (int ri = 0; ri < 2; ri++)
        #pragma unroll
        for (int nt = 0; nt < 4; nt++) acc[ri][nt] = (float4v){0.f, 0.f, 0.f, 0.f};

    #pragma unroll
    for (int t = 0; t < 6; t++) {
        const int srow = wv * 2 + t;
        #pragma unroll
        for (int kx = 0; kx < 5; kx++) {
            short8 a0, a1;
            if (t <= 4) a0 = *(const short8*)(wf3 + (((t * 5 + kx) * 64 + lane)) * 8);
            if (t >= 1) a1 = *(const short8*)(wf3 + ((((t - 1) * 5 + kx) * 64 + lane)) * 8);
            const int boff = (srow * 68 + n + kx) * 40 + q * 8;
            #pragma unroll
            for (int nt = 0; nt < 4; nt++) {
                short8 bfr = *(const short8*)(slab + boff + nt * 640);
                if (t <= 4) acc[0][nt] = __builtin_amdgcn_mfma_f32_16x16x32_bf16(a0, bfr, acc[0][nt], 0, 0, 0);
                if (t >= 1) acc[1][nt] = __builtin_amdgcn_mfma_f32_16x16x32_bf16(a1, bfr, acc[1][nt], 0, 0, 0);
            }
        }
    }

    const float bi = bias[0];
    if (q == 0) {
        #pragma unroll
        for (int ri = 0; ri < 2; ri++) {
            const int y = ybase + wv * 2 + ri;
            if (y < H) {
                #pragma unroll
                for (int nt = 0; nt < 4; nt++) {
                    const int x = xbase + nt * 16 + n;
                    if (x < W) out[((size_t)b * H + y) * W + x] = acc[ri][nt].x + bi;
                }
            }
        }
    }
}

// ---------------------------------------------------------------------------
extern "C" void kernel_launch(void* const* d_in, const int* in_sizes, int n_in,
                              void* d_out, int out_size, void* d_ws, size_t ws_size,
                              hipStream_t stream) {
    const float* x        = (const float*)d_in[0];
    const float* elev0    = (const float*)d_in[1];
    const float* elev1    = (const float*)d_in[2];
    const int*   psi_idx1 = (const int*)  d_in[3];
    const float* psi_val1 = (const float*)d_in[4];
    const float* w1       = (const float*)d_in[5];
    const float* b1       = (const float*)d_in[6];
    const float* cw2_1    = (const float*)d_in[7];
    const float* cb2_1    = (const float*)d_in[8];
    const float* cw3_1    = (const float*)d_in[9];
    const float* cb3_1    = (const float*)d_in[10];
    const int*   psi_idx2 = (const int*)  d_in[11];
    const float* psi_val2 = (const float*)d_in[12];
    const float* w2       = (const float*)d_in[13];
    const float* b2       = (const float*)d_in[14];
    const float* cw2_2    = (const float*)d_in[15];
    const float* cb2_2    = (const float*)d_in[16];
    const float* cw3_2    = (const float*)d_in[17];
    const float* cb3_2    = (const float*)d_in[18];

    const int B = 4;
    const int H1 = 180, W1 = 360, P1 = H1 * W1;
    const int H2 = 360, W2 = 720, P2 = H2 * W2;

    // workspace layout (bytes); u2i overlaps the tail of c (stage-1 c uses
    // only the first 16.6 MB; u2i is dead before conv2_2 rewrites c).
    char* ws = (char*)d_ws;
    short* h    = (short*)(ws);                      // 132,710,400
    short* c    = (short*)(ws + 132710400);          //  66,355,200
    float* u2i  = (float*)(ws + 149299200);          //   8,294,400 (inside c tail)
    float* u1i  = (float*)(ws + 199065600);          //   2,073,600
    float* s1   = (float*)(ws + 201139200);          //   1,036,800
    short* wfA  = (short*)(ws + 202176000);          //     102,400
    short* wfB  = (short*)(ws + 202278400);          //     102,400
    short* wfD1 = (short*)(ws + 202380800);          //       4,096
    short* wfD2 = (short*)(ws + 202384896);          //       4,096
    short* wf31 = (short*)(ws + 202388992);          //      25,600
    short* wf32 = (short*)(ws + 202414592);          //      25,600
    (void)ws_size; (void)in_sizes; (void)n_in; (void)out_size;

    packall_k<<<(132096 + 255) / 256, 256, 0, stream>>>(
        cw2_1, cw2_2, cw3_1, cw3_2, w1, w2, wfA, wfB, wf31, wf32, wfD1, wfD2);

    // ---- stage 1 ----
    upsample_pack_k<<<(B * P1 + 255) / 256, 256, 0, stream>>>(x, elev0, u1i, B, 90, 180);
    disco_k<<<(P1 + 255) / 256, 256, 0, stream>>>(
        u1i, psi_idx1, psi_val1, wfD1, b1, h, P1);
    conv2_k<<<dim3((W1 + 63) / 64, (H1 + 7) / 8, B), 256, 0, stream>>>(
        h, wfA, cb2_1, c, H1, W1);
    conv3_k<<<dim3((W1 + 63) / 64, (H1 + 7) / 8, B), 256, 0, stream>>>(
        c, wf31, cb3_1, s1, H1, W1);

    // ---- stage 2 ----
    upsample_pack_k<<<(B * P2 + 255) / 256, 256, 0, stream>>>(s1, elev1, u2i, B, H1, W1);
    disco_k<<<(P2 + 255) / 256, 256, 0, stream>>>(
        u2i, psi_idx2, psi_val2, wfD2, b2, h, P2);
    conv2_k<<<dim3((W2 + 63) / 64, (H2 + 7) / 8, B), 256, 0, stream>>>(
        h, wfB, cb2_2, c, H2, W2);
    conv3_k<<<dim3((W2 + 63) / 64, (H2 + 7) / 8, B), 256, 0, stream>>>(
        c, wf32, cb3_2, (float*)d_out, H2, W2);
}

// Round 6
// 491.903 us; speedup vs baseline: 4.3501x; 1.1037x over previous
//
#include <hip/hip_runtime.h>
#include <hip/hip_bf16.h>

typedef __hip_bfloat16 bf16;
typedef __attribute__((ext_vector_type(8))) short short8;
typedef __attribute__((ext_vector_type(4))) short short4v;
typedef __attribute__((ext_vector_type(4))) float float4v;

__device__ __forceinline__ short f2bs(float x) {
    bf16 b = __float2bfloat16(x);
    return *reinterpret_cast<short*>(&b);
}

// wave-local LDS fence: order ds_write -> ds_read within one wave without a
// workgroup barrier (zs regions are wave-private in disco_k).
__device__ __forceinline__ void wave_lds_fence() {
    __builtin_amdgcn_wave_barrier();
    __builtin_amdgcn_s_waitcnt(0xC07F);   // lgkmcnt(0), vmcnt/expcnt untouched
    __builtin_amdgcn_wave_barrier();
}

// ---------------------------------------------------------------------------
// Bilinear 2x upsample + pack with elev: out2[i] = {upsampled(i), elev(i)}.
// ---------------------------------------------------------------------------
__global__ void upsample_pack_k(const float* __restrict__ in,
                                const float* __restrict__ elev,
                                float* __restrict__ out2, int B, int H, int W) {
    const int OH = 2 * H, OW = 2 * W;
    const long total = (long)B * OH * OW;
    long i = (long)blockIdx.x * blockDim.x + threadIdx.x;
    if (i >= total) return;
    int ox = (int)(i % OW);
    long r = i / OW;
    int oy = (int)(r % OH);
    int b  = (int)(r / OH);
    float sy = fminf(fmaxf(oy * 0.5f - 0.25f, 0.0f), (float)(H - 1));
    float sx = fminf(fmaxf(ox * 0.5f - 0.25f, 0.0f), (float)(W - 1));
    int y0 = (int)sy; float ty = sy - (float)y0; int y1 = min(y0 + 1, H - 1);
    int x0 = (int)sx; float tx = sx - (float)x0; int x1 = min(x0 + 1, W - 1);
    const float* p = in + (size_t)b * H * W;
    float v00 = p[(size_t)y0 * W + x0];
    float v01 = p[(size_t)y0 * W + x1];
    float v10 = p[(size_t)y1 * W + x0];
    float v11 = p[(size_t)y1 * W + x1];
    float v = (v00 * (1.f - ty) + v10 * ty) * (1.f - tx)
            + (v01 * (1.f - ty) + v11 * ty) * tx;
    float2 o; o.x = v; o.y = elev[i];
    *(float2*)(out2 + i * 2) = o;
}

// ---------------------------------------------------------------------------
// Fused weight packs (all six arrays in one launch). Layouts as round 5.
// ---------------------------------------------------------------------------
__global__ void packall_k(const float* __restrict__ cw2_1, const float* __restrict__ cw2_2,
                          const float* __restrict__ cw3_1, const float* __restrict__ cw3_2,
                          const float* __restrict__ w1,    const float* __restrict__ w2,
                          short* __restrict__ wfA,  short* __restrict__ wfB,
                          short* __restrict__ wf31, short* __restrict__ wf32,
                          short* __restrict__ wfD1, short* __restrict__ wfD2) {
    int gi = blockIdx.x * 256 + threadIdx.x;
    if (gi < 102400) {
        const float* src = (gi < 51200) ? cw2_1 : cw2_2;
        short* dst       = (gi < 51200) ? wfA   : wfB;
        int i = (gi < 51200) ? gi : gi - 51200;
        int j    = i & 7;
        int r    = i >> 3;
        int lane = r & 63;
        int r2   = r >> 6;
        int mt   = r2 & 1;
        int r3   = r2 >> 1;
        int tap  = r3 % 25;
        int icc  = r3 / 25;
        int m = lane & 15, q = lane >> 4;
        int oc = mt * 16 + m;
        int ic = icc * 32 + q * 8 + j;
        dst[i] = f2bs(src[((size_t)oc * 64 + ic) * 25 + tap]);
    } else if (gi < 128000) {
        int gi2 = gi - 102400;
        const float* src = (gi2 < 12800) ? cw3_1 : cw3_2;
        short* dst       = (gi2 < 12800) ? wf31  : wf32;
        int i = (gi2 < 12800) ? gi2 : gi2 - 12800;
        int j    = i & 7;
        int r    = i >> 3;
        int lane = r & 63;
        int tap  = r >> 6;
        int m = lane & 15, q = lane >> 4;
        dst[i] = (m == 0) ? f2bs(src[(size_t)(q * 8 + j) * 25 + tap]) : (short)0;
    } else if (gi < 132096) {
        int gi2 = gi - 128000;
        const float* src = (gi2 < 2048) ? w1 : w2;
        short* dst       = (gi2 < 2048) ? wfD1 : wfD2;
        int i = (gi2 < 2048) ? gi2 : gi2 - 2048;
        int j = i & 7;
        int r = i >> 3;
        int lane = r & 63;
        int mtile = r >> 6;
        int q = lane >> 4, mm = lane & 15;
        int oc = mtile * 16 + mm;
        int k = q * 8 + j;
        dst[i] = (k < 18) ? f2bs(src[oc * 18 + k]) : (short)0;
    }
}

// ---------------------------------------------------------------------------
// disco conv with MFMA output matmul. zs is wave-private (wave wv writes rows
// 64wv..64wv+63 in phase 1 and reads exactly those rows in phase 2), so the
// per-batch __syncthreads() pairs are replaced by wave-local LDS fences —
// batch b+1 gathers overlap batch b MFMA/stores.
// ---------------------------------------------------------------------------
__global__ __launch_bounds__(256)
void disco_k(const float* __restrict__ ui,
             const int* __restrict__ psi_idx, const float* __restrict__ psi_val,
             const short* __restrict__ wfragD, const float* __restrict__ bias,
             short* __restrict__ outh, int P) {
    __shared__ short zs[256 * 40];
    const int tid  = threadIdx.x;
    const int lane = tid & 63;
    const int wv   = tid >> 6;
    const int q    = lane >> 4;
    const int n    = lane & 15;

    for (int c0 = 0; c0 < 40; c0 += 8) *(short8*)(zs + tid * 40 + c0) = (short8)0;

    short8 af[4];
    float brg[4][4];
    #pragma unroll
    for (int mt = 0; mt < 4; mt++) {
        af[mt] = *(const short8*)(wfragD + ((mt * 64 + lane) << 3));
        #pragma unroll
        for (int r = 0; r < 4; r++) brg[mt][r] = bias[mt * 16 + q * 4 + r];
    }

    const int p = blockIdx.x * 256 + tid;
    const bool valid = p < P;

    int idx[8];
    float pv[9][8];
    if (valid) {
        const int* ip = psi_idx + (size_t)p * 8;
        int4 ia = *(const int4*)ip;
        int4 ib = *(const int4*)(ip + 4);
        idx[0]=ia.x; idx[1]=ia.y; idx[2]=ia.z; idx[3]=ia.w;
        idx[4]=ib.x; idx[5]=ib.y; idx[6]=ib.z; idx[7]=ib.w;
        #pragma unroll
        for (int k = 0; k < 9; k++) {
            const float* qp = psi_val + ((size_t)k * P + p) * 8;
            float4 qa = *(const float4*)qp;
            float4 qb = *(const float4*)(qp + 4);
            pv[k][0]=qa.x; pv[k][1]=qa.y; pv[k][2]=qa.z; pv[k][3]=qa.w;
            pv[k][4]=qb.x; pv[k][5]=qb.y; pv[k][6]=qb.z; pv[k][7]=qb.w;
        }
    }

    for (int bq = 0; bq < 4; bq++) {
        if (valid) {
            const float* ub = ui + (size_t)bq * P * 2;
            float g0[8], g1[8];
            #pragma unroll
            for (int t = 0; t < 8; t++) {
                float2 g = *(const float2*)(ub + (size_t)idx[t] * 2);
                g0[t] = g.x; g1[t] = g.y;
            }
            float z[18];
            #pragma unroll
            for (int j = 0; j < 18; j++) z[j] = 0.f;
            #pragma unroll
            for (int k = 0; k < 9; k++) {
                #pragma unroll
                for (int t = 0; t < 8; t++) {
                    z[k]     = fmaf(g0[t], pv[k][t], z[k]);
                    z[9 + k] = fmaf(g1[t], pv[k][t], z[9 + k]);
                }
            }
            #pragma unroll
            for (int c0i = 0; c0i < 16; c0i += 4) {
                short4v t4;
                t4.x = f2bs(z[c0i]); t4.y = f2bs(z[c0i+1]);
                t4.z = f2bs(z[c0i+2]); t4.w = f2bs(z[c0i+3]);
                *(short4v*)(zs + tid * 40 + c0i) = t4;
            }
            unsigned int lo = (unsigned short)f2bs(z[16]);
            unsigned int hi = (unsigned short)f2bs(z[17]);
            *(unsigned int*)(zs + tid * 40 + 16) = lo | (hi << 16);
        }
        wave_lds_fence();     // writes (own wave) -> reads (own wave)

        #pragma unroll
        for (int t = 0; t < 4; t++) {
            const int nt  = wv * 4 + t;
            const int pix = blockIdx.x * 256 + nt * 16 + n;
            short8 bz = *(const short8*)(zs + (nt * 16 + n) * 40 + q * 8);
            const bool pok = pix < P;
            short* hp = outh + ((size_t)bq * P + pix) * 64;
            #pragma unroll
            for (int mt = 0; mt < 4; mt++) {
                float4v acc = {0.f, 0.f, 0.f, 0.f};
                acc = __builtin_amdgcn_mfma_f32_16x16x32_bf16(af[mt], bz, acc, 0, 0, 0);
                if (pok) {
                    short4v o;
                    o.x = f2bs(fmaxf(acc.x + brg[mt][0], 0.f));
                    o.y = f2bs(fmaxf(acc.y + brg[mt][1], 0.f));
                    o.z = f2bs(fmaxf(acc.z + brg[mt][2], 0.f));
                    o.w = f2bs(fmaxf(acc.w + brg[mt][3], 0.f));
                    *(short4v*)(hp + mt * 16 + q * 4) = o;
                }
            }
        }
        wave_lds_fence();     // reads done before next batch overwrites
    }
}

// ---------------------------------------------------------------------------
// conv2 implicit-GEMM MFMA, 2 output rows per wave, 32px x 8row tile.
// Slab [12 rows][36 cols][40 kslots] bf16 = 34,560 B -> 4 blocks/CU.
// Same 2-row B-frag reuse as round 5; occupancy restored.
// ---------------------------------------------------------------------------
__global__ __launch_bounds__(256, 4)
void conv2_k(const short* __restrict__ hS, const short* __restrict__ wfrag,
             const float* __restrict__ bias, short* __restrict__ outc,
             int H, int W) {
    __shared__ short slab[12 * 36 * 40];   // 34,560 B
    const int tid  = threadIdx.x;
    const int wv   = tid >> 6;
    const int lane = tid & 63;
    const int q    = lane >> 4;
    const int n    = lane & 15;
    const int xbase = blockIdx.x * 32;
    const int ybase = blockIdx.y * 8;
    const int b     = blockIdx.z;
    const short* hb = hS + (size_t)b * H * W * 64;

    float4v acc[2][2][2];   // [row][nt][mt]
    #pragma unroll
    for (int ri = 0; ri < 2; ri++)
        #pragma unroll
        for (int nt = 0; nt < 2; nt++)
            #pragma unroll
            for (int mt = 0; mt < 2; mt++)
                acc[ri][nt][mt] = (float4v){0.f, 0.f, 0.f, 0.f};

    float brg[2][4];
    #pragma unroll
    for (int mt = 0; mt < 2; mt++)
        #pragma unroll
        for (int r = 0; r < 4; r++) brg[mt][r] = bias[mt * 16 + q * 4 + r];

    for (int icc = 0; icc < 2; icc++) {
        __syncthreads();
        for (int l = tid; l < 1728; l += 256) {      // 12*36*4 16B-chunks
            int qq  = l & 3;
            int pix = l >> 2;            // row*36+col
            int row = pix / 36;
            int col = pix - row * 36;
            int gy = ybase - 2 + row;
            int gx = xbase - 2 + col;
            short8 v = (short8)0;
            if ((unsigned)gy < (unsigned)H && (unsigned)gx < (unsigned)W)
                v = *(const short8*)(hb + ((size_t)gy * W + gx) * 64 + icc * 32 + qq * 8);
            *(short8*)(slab + pix * 40 + qq * 8) = v;
        }
        __syncthreads();

        const short* wfr = wfrag + (size_t)icc * 25600;
        #pragma unroll
        for (int t = 0; t < 6; t++) {                // slab row = wv*2 + t
            const int srow = wv * 2 + t;
            #pragma unroll
            for (int kx = 0; kx < 5; kx++) {
                short8 w0a, w0b, w1a, w1b;
                if (t <= 4) {                        // row0 tap (ky=t, kx)
                    const int tp = t * 5 + kx;
                    w0a = *(const short8*)(wfr + ((tp * 2 + 0) * 64 + lane) * 8);
                    w0b = *(const short8*)(wfr + ((tp * 2 + 1) * 64 + lane) * 8);
                }
                if (t >= 1) {                        // row1 tap (ky=t-1, kx)
                    const int tp = (t - 1) * 5 + kx;
                    w1a = *(const short8*)(wfr + ((tp * 2 + 0) * 64 + lane) * 8);
                    w1b = *(const short8*)(wfr + ((tp * 2 + 1) * 64 + lane) * 8);
                }
                const int boff = (srow * 36 + n + kx) * 40 + q * 8;
                #pragma unroll
                for (int nt = 0; nt < 2; nt++) {
                    short8 bfr = *(const short8*)(slab + boff + nt * 640);
                    if (t <= 4) {
                        acc[0][nt][0] = __builtin_amdgcn_mfma_f32_16x16x32_bf16(w0a, bfr, acc[0][nt][0], 0, 0, 0);
                        acc[0][nt][1] = __builtin_amdgcn_mfma_f32_16x16x32_bf16(w0b, bfr, acc[0][nt][1], 0, 0, 0);
                    }
                    if (t >= 1) {
                        acc[1][nt][0] = __builtin_amdgcn_mfma_f32_16x16x32_bf16(w1a, bfr, acc[1][nt][0], 0, 0, 0);
                        acc[1][nt][1] = __builtin_amdgcn_mfma_f32_16x16x32_bf16(w1b, bfr, acc[1][nt][1], 0, 0, 0);
                    }
                }
            }
        }
    }

    #pragma unroll
    for (int ri = 0; ri < 2; ri++) {
        const int y = ybase + wv * 2 + ri;
        if (y < H) {
            #pragma unroll
            for (int nt = 0; nt < 2; nt++) {
                const int x = xbase + nt * 16 + n;
                if (x < W) {
                    short* cp = outc + (((size_t)b * H * W + (size_t)y * W + x) * 32);
                    #pragma unroll
                    for (int mt = 0; mt < 2; mt++) {
                        short4v o;
                        o.x = f2bs(fmaxf(acc[ri][nt][mt].x + brg[mt][0], 0.f));
                        o.y = f2bs(fmaxf(acc[ri][nt][mt].y + brg[mt][1], 0.f));
                        o.z = f2bs(fmaxf(acc[ri][nt][mt].z + brg[mt][2], 0.f));
                        o.w = f2bs(fmaxf(acc[ri][nt][mt].w + brg[mt][3], 0.f));
                        *(short4v*)(cp + mt * 16 + q * 4) = o;
                    }
                }
            }
        }
    }
}

// ---------------------------------------------------------------------------
// conv3 implicit-GEMM MFMA, 2 output rows per wave, 32px x 8row tile.
// IC=32 -> OC=1 (M padded to 16), +bias. Slab [12][36][40] = 34,560 B.
// ---------------------------------------------------------------------------
__global__ __launch_bounds__(256, 4)
void conv3_k(const short* __restrict__ cP, const short* __restrict__ wf3,
             const float* __restrict__ bias, float* __restrict__ out,
             int H, int W) {
    __shared__ short slab[12 * 36 * 40];
    const int tid  = threadIdx.x;
    const int wv   = tid >> 6;
    const int lane = tid & 63;
    const int q    = lane >> 4;
    const int n    = lane & 15;
    const int xbase = blockIdx.x * 32;
    const int ybase = blockIdx.y * 8;
    const int b     = blockIdx.z;
    const short* cb = cP + (size_t)b * H * W * 32;

    for (int l = tid; l < 1728; l += 256) {
        int qq  = l & 3;
        int pix = l >> 2;
        int row = pix / 36;
        int col = pix - row * 36;
        int gy = ybase - 2 + row;
        int gx = xbase - 2 + col;
        short8 v = (short8)0;
        if ((unsigned)gy < (unsigned)H && (unsigned)gx < (unsigned)W)
            v = *(const short8*)(cb + ((size_t)gy * W + gx) * 32 + qq * 8);
        *(short8*)(slab + pix * 40 + qq * 8) = v;
    }
    __syncthreads();

    float4v acc[2][2];
    #pragma unroll
    for (int ri = 0; ri < 2; ri++)
        #pragma unroll
        for (int nt = 0; nt < 2; nt++) acc[ri][nt] = (float4v){0.f, 0.f, 0.f, 0.f};

    #pragma unroll
    for (int t = 0; t < 6; t++) {
        const int srow = wv * 2 + t;
        #pragma unroll
        for (int kx = 0; kx < 5; kx++) {
            short8 a0, a1;
            if (t <= 4) a0 = *(const short8*)(wf3 + (((t * 5 + kx) * 64 + lane)) * 8);
            if (t >= 1) a1 = *(const short8*)(wf3 + ((((t - 1) * 5 + kx) * 64 + lane)) * 8);
            const int boff = (srow * 36 + n + kx) * 40 + q * 8;
            #pragma unroll
            for (int nt = 0; nt < 2; nt++) {
                short8 bfr = *(const short8*)(slab + boff + nt * 640);
                if (t <= 4) acc[0][nt] = __builtin_amdgcn_mfma_f32_16x16x32_bf16(a0, bfr, acc[0][nt], 0, 0, 0);
                if (t >= 1) acc[1][nt] = __builtin_amdgcn_mfma_f32_16x16x32_bf16(a1, bfr, acc[1][nt], 0, 0, 0);
            }
        }
    }

    const float bi = bias[0];
    if (q == 0) {
        #pragma unroll
        for (int ri = 0; ri < 2; ri++) {
            const int y = ybase + wv * 2 + ri;
            if (y < H) {
                #pragma unroll
                for (int nt = 0; nt < 2; nt++) {
                    const int x = xbase + nt * 16 + n;
                    if (x < W) out[((size_t)b * H + y) * W + x] = acc[ri][nt].x + bi;
                }
            }
        }
    }
}

// ---------------------------------------------------------------------------
extern "C" void kernel_launch(void* const* d_in, const int* in_sizes, int n_in,
                              void* d_out, int out_size, void* d_ws, size_t ws_size,
                              hipStream_t stream) {
    const float* x        = (const float*)d_in[0];
    const float* elev0    = (const float*)d_in[1];
    const float* elev1    = (const float*)d_in[2];
    const int*   psi_idx1 = (const int*)  d_in[3];
    const float* psi_val1 = (const float*)d_in[4];
    const float* w1       = (const float*)d_in[5];
    const float* b1       = (const float*)d_in[6];
    const float* cw2_1    = (const float*)d_in[7];
    const float* cb2_1    = (const float*)d_in[8];
    const float* cw3_1    = (const float*)d_in[9];
    const float* cb3_1    = (const float*)d_in[10];
    const int*   psi_idx2 = (const int*)  d_in[11];
    const float* psi_val2 = (const float*)d_in[12];
    const float* w2       = (const float*)d_in[13];
    const float* b2       = (const float*)d_in[14];
    const float* cw2_2    = (const float*)d_in[15];
    const float* cb2_2    = (const float*)d_in[16];
    const float* cw3_2    = (const float*)d_in[17];
    const float* cb3_2    = (const float*)d_in[18];

    const int B = 4;
    const int H1 = 180, W1 = 360, P1 = H1 * W1;
    const int H2 = 360, W2 = 720, P2 = H2 * W2;

    // workspace layout (bytes); u2i overlaps the tail of c (stage-1 c uses
    // only the first 16.6 MB; u2i is dead before conv2_2 rewrites c).
    char* ws = (char*)d_ws;
    short* h    = (short*)(ws);                      // 132,710,400
    short* c    = (short*)(ws + 132710400);          //  66,355,200
    float* u2i  = (float*)(ws + 149299200);          //   8,294,400 (inside c tail)
    float* u1i  = (float*)(ws + 199065600);          //   2,073,600
    float* s1   = (float*)(ws + 201139200);          //   1,036,800
    short* wfA  = (short*)(ws + 202176000);          //     102,400
    short* wfB  = (short*)(ws + 202278400);          //     102,400
    short* wfD1 = (short*)(ws + 202380800);          //       4,096
    short* wfD2 = (short*)(ws + 202384896);          //       4,096
    short* wf31 = (short*)(ws + 202388992);          //      25,600
    short* wf32 = (short*)(ws + 202414592);          //      25,600
    (void)ws_size; (void)in_sizes; (void)n_in; (void)out_size;

    packall_k<<<(132096 + 255) / 256, 256, 0, stream>>>(
        cw2_1, cw2_2, cw3_1, cw3_2, w1, w2, wfA, wfB, wf31, wf32, wfD1, wfD2);

    // ---- stage 1 ----
    upsample_pack_k<<<(B * P1 + 255) / 256, 256, 0, stream>>>(x, elev0, u1i, B, 90, 180);
    disco_k<<<(P1 + 255) / 256, 256, 0, stream>>>(
        u1i, psi_idx1, psi_val1, wfD1, b1, h, P1);
    conv2_k<<<dim3((W1 + 31) / 32, (H1 + 7) / 8, B), 256, 0, stream>>>(
        h, wfA, cb2_1, c, H1, W1);
    conv3_k<<<dim3((W1 + 31) / 32, (H1 + 7) / 8, B), 256, 0, stream>>>(
        c, wf31, cb3_1, s1, H1, W1);

    // ---- stage 2 ----
    upsample_pack_k<<<(B * P2 + 255) / 256, 256, 0, stream>>>(s1, elev1, u2i, B, H1, W1);
    disco_k<<<(P2 + 255) / 256, 256, 0, stream>>>(
        u2i, psi_idx2, psi_val2, wfD2, b2, h, P2);
    conv2_k<<<dim3((W2 + 31) / 32, (H2 + 7) / 8, B), 256, 0, stream>>>(
        h, wfB, cb2_2, c, H2, W2);
    conv3_k<<<dim3((W2 + 31) / 32, (H2 + 7) / 8, B), 256, 0, stream>>>(
        c, wf32, cb3_2, (float*)d_out, H2, W2);
}

// Round 7
// 476.336 us; speedup vs baseline: 4.4923x; 1.0327x over previous
//
#include <hip/hip_runtime.h>
#include <hip/hip_bf16.h>

typedef __hip_bfloat16 bf16;
typedef __attribute__((ext_vector_type(8))) short short8;
typedef __attribute__((ext_vector_type(4))) short short4v;
typedef __attribute__((ext_vector_type(4))) float float4v;

__device__ __forceinline__ short f2bs(float x) {
    bf16 b = __float2bfloat16(x);
    return *reinterpret_cast<short*>(&b);
}

// wave-local LDS fence: order ds_write -> ds_read within one wave without a
// workgroup barrier (zs regions are wave-private in disco_k).
__device__ __forceinline__ void wave_lds_fence() {
    __builtin_amdgcn_wave_barrier();
    __builtin_amdgcn_s_waitcnt(0xC07F);   // lgkmcnt(0), vmcnt/expcnt untouched
    __builtin_amdgcn_wave_barrier();
}

// ---------------------------------------------------------------------------
// Bilinear 2x upsample + pack with elev: out2[i] = {upsampled(i), elev(i)}.
// ---------------------------------------------------------------------------
__global__ void upsample_pack_k(const float* __restrict__ in,
                                const float* __restrict__ elev,
                                float* __restrict__ out2, int B, int H, int W) {
    const int OH = 2 * H, OW = 2 * W;
    const long total = (long)B * OH * OW;
    long i = (long)blockIdx.x * blockDim.x + threadIdx.x;
    if (i >= total) return;
    int ox = (int)(i % OW);
    long r = i / OW;
    int oy = (int)(r % OH);
    int b  = (int)(r / OH);
    float sy = fminf(fmaxf(oy * 0.5f - 0.25f, 0.0f), (float)(H - 1));
    float sx = fminf(fmaxf(ox * 0.5f - 0.25f, 0.0f), (float)(W - 1));
    int y0 = (int)sy; float ty = sy - (float)y0; int y1 = min(y0 + 1, H - 1);
    int x0 = (int)sx; float tx = sx - (float)x0; int x1 = min(x0 + 1, W - 1);
    const float* p = in + (size_t)b * H * W;
    float v00 = p[(size_t)y0 * W + x0];
    float v01 = p[(size_t)y0 * W + x1];
    float v10 = p[(size_t)y1 * W + x0];
    float v11 = p[(size_t)y1 * W + x1];
    float v = (v00 * (1.f - ty) + v10 * ty) * (1.f - tx)
            + (v01 * (1.f - ty) + v11 * ty) * tx;
    float2 o; o.x = v; o.y = elev[i];
    *(float2*)(out2 + i * 2) = o;
}

// ---------------------------------------------------------------------------
// Fused weight packs (all six arrays in one launch). Layouts as round 5.
// ---------------------------------------------------------------------------
__global__ void packall_k(const float* __restrict__ cw2_1, const float* __restrict__ cw2_2,
                          const float* __restrict__ cw3_1, const float* __restrict__ cw3_2,
                          const float* __restrict__ w1,    const float* __restrict__ w2,
                          short* __restrict__ wfA,  short* __restrict__ wfB,
                          short* __restrict__ wf31, short* __restrict__ wf32,
                          short* __restrict__ wfD1, short* __restrict__ wfD2) {
    int gi = blockIdx.x * 256 + threadIdx.x;
    if (gi < 102400) {
        const float* src = (gi < 51200) ? cw2_1 : cw2_2;
        short* dst       = (gi < 51200) ? wfA   : wfB;
        int i = (gi < 51200) ? gi : gi - 51200;
        int j    = i & 7;
        int r    = i >> 3;
        int lane = r & 63;
        int r2   = r >> 6;
        int mt   = r2 & 1;
        int r3   = r2 >> 1;
        int tap  = r3 % 25;
        int icc  = r3 / 25;
        int m = lane & 15, q = lane >> 4;
        int oc = mt * 16 + m;
        int ic = icc * 32 + q * 8 + j;
        dst[i] = f2bs(src[((size_t)oc * 64 + ic) * 25 + tap]);
    } else if (gi < 128000) {
        int gi2 = gi - 102400;
        const float* src = (gi2 < 12800) ? cw3_1 : cw3_2;
        short* dst       = (gi2 < 12800) ? wf31  : wf32;
        int i = (gi2 < 12800) ? gi2 : gi2 - 12800;
        int j    = i & 7;
        int r    = i >> 3;
        int lane = r & 63;
        int tap  = r >> 6;
        int m = lane & 15, q = lane >> 4;
        dst[i] = (m == 0) ? f2bs(src[(size_t)(q * 8 + j) * 25 + tap]) : (short)0;
    } else if (gi < 132096) {
        int gi2 = gi - 128000;
        const float* src = (gi2 < 2048) ? w1 : w2;
        short* dst       = (gi2 < 2048) ? wfD1 : wfD2;
        int i = (gi2 < 2048) ? gi2 : gi2 - 2048;
        int j = i & 7;
        int r = i >> 3;
        int lane = r & 63;
        int mtile = r >> 6;
        int q = lane >> 4, mm = lane & 15;
        int oc = mtile * 16 + mm;
        int k = q * 8 + j;
        dst[i] = (k < 18) ? f2bs(src[oc * 18 + k]) : (short)0;
    }
}

// ---------------------------------------------------------------------------
// disco conv with MFMA output matmul (unchanged from round 6).
// ---------------------------------------------------------------------------
__global__ __launch_bounds__(256)
void disco_k(const float* __restrict__ ui,
             const int* __restrict__ psi_idx, const float* __restrict__ psi_val,
             const short* __restrict__ wfragD, const float* __restrict__ bias,
             short* __restrict__ outh, int P) {
    __shared__ short zs[256 * 40];
    const int tid  = threadIdx.x;
    const int lane = tid & 63;
    const int wv   = tid >> 6;
    const int q    = lane >> 4;
    const int n    = lane & 15;

    for (int c0 = 0; c0 < 40; c0 += 8) *(short8*)(zs + tid * 40 + c0) = (short8)0;

    short8 af[4];
    float brg[4][4];
    #pragma unroll
    for (int mt = 0; mt < 4; mt++) {
        af[mt] = *(const short8*)(wfragD + ((mt * 64 + lane) << 3));
        #pragma unroll
        for (int r = 0; r < 4; r++) brg[mt][r] = bias[mt * 16 + q * 4 + r];
    }

    const int p = blockIdx.x * 256 + tid;
    const bool valid = p < P;

    int idx[8];
    float pv[9][8];
    if (valid) {
        const int* ip = psi_idx + (size_t)p * 8;
        int4 ia = *(const int4*)ip;
        int4 ib = *(const int4*)(ip + 4);
        idx[0]=ia.x; idx[1]=ia.y; idx[2]=ia.z; idx[3]=ia.w;
        idx[4]=ib.x; idx[5]=ib.y; idx[6]=ib.z; idx[7]=ib.w;
        #pragma unroll
        for (int k = 0; k < 9; k++) {
            const float* qp = psi_val + ((size_t)k * P + p) * 8;
            float4 qa = *(const float4*)qp;
            float4 qb = *(const float4*)(qp + 4);
            pv[k][0]=qa.x; pv[k][1]=qa.y; pv[k][2]=qa.z; pv[k][3]=qa.w;
            pv[k][4]=qb.x; pv[k][5]=qb.y; pv[k][6]=qb.z; pv[k][7]=qb.w;
        }
    }

    for (int bq = 0; bq < 4; bq++) {
        if (valid) {
            const float* ub = ui + (size_t)bq * P * 2;
            float g0[8], g1[8];
            #pragma unroll
            for (int t = 0; t < 8; t++) {
                float2 g = *(const float2*)(ub + (size_t)idx[t] * 2);
                g0[t] = g.x; g1[t] = g.y;
            }
            float z[18];
            #pragma unroll
            for (int j = 0; j < 18; j++) z[j] = 0.f;
            #pragma unroll
            for (int k = 0; k < 9; k++) {
                #pragma unroll
                for (int t = 0; t < 8; t++) {
                    z[k]     = fmaf(g0[t], pv[k][t], z[k]);
                    z[9 + k] = fmaf(g1[t], pv[k][t], z[9 + k]);
                }
            }
            #pragma unroll
            for (int c0i = 0; c0i < 16; c0i += 4) {
                short4v t4;
                t4.x = f2bs(z[c0i]); t4.y = f2bs(z[c0i+1]);
                t4.z = f2bs(z[c0i+2]); t4.w = f2bs(z[c0i+3]);
                *(short4v*)(zs + tid * 40 + c0i) = t4;
            }
            unsigned int lo = (unsigned short)f2bs(z[16]);
            unsigned int hi = (unsigned short)f2bs(z[17]);
            *(unsigned int*)(zs + tid * 40 + 16) = lo | (hi << 16);
        }
        wave_lds_fence();     // writes (own wave) -> reads (own wave)

        #pragma unroll
        for (int t = 0; t < 4; t++) {
            const int nt  = wv * 4 + t;
            const int pix = blockIdx.x * 256 + nt * 16 + n;
            short8 bz = *(const short8*)(zs + (nt * 16 + n) * 40 + q * 8);
            const bool pok = pix < P;
            short* hp = outh + ((size_t)bq * P + pix) * 64;
            #pragma unroll
            for (int mt = 0; mt < 4; mt++) {
                float4v acc = {0.f, 0.f, 0.f, 0.f};
                acc = __builtin_amdgcn_mfma_f32_16x16x32_bf16(af[mt], bz, acc, 0, 0, 0);
                if (pok) {
                    short4v o;
                    o.x = f2bs(fmaxf(acc.x + brg[mt][0], 0.f));
                    o.y = f2bs(fmaxf(acc.y + brg[mt][1], 0.f));
                    o.z = f2bs(fmaxf(acc.z + brg[mt][2], 0.f));
                    o.w = f2bs(fmaxf(acc.w + brg[mt][3], 0.f));
                    *(short4v*)(hp + mt * 16 + q * 4) = o;
                }
            }
        }
        wave_lds_fence();     // reads done before next batch overwrites
    }
}

// ---------------------------------------------------------------------------
// conv2 implicit-GEMM MFMA, 2 output rows per wave, 32px x 8row tile.
// Slab [12 rows][36 cols][40 kslots] bf16 = 34,560 B.
// K-loop restructured kx-outer with a double-buffered weight register file:
// wbuf[cur] holds all 10 frags of column kx (loaded once per tap — row1's
// ky=t-1 tap is wbuf[cur][t-1]); wbuf[cur^1] is prefetched one full kx column
// (~240 cyc) ahead, hiding L2 latency. Weight loads halve vs round 6.
// ---------------------------------------------------------------------------
__global__ __launch_bounds__(256, 3)
void conv2_k(const short* __restrict__ hS, const short* __restrict__ wfrag,
             const float* __restrict__ bias, short* __restrict__ outc,
             int H, int W) {
    __shared__ short slab[12 * 36 * 40];   // 34,560 B
    const int tid  = threadIdx.x;
    const int wv   = tid >> 6;
    const int lane = tid & 63;
    const int q    = lane >> 4;
    const int n    = lane & 15;
    const int xbase = blockIdx.x * 32;
    const int ybase = blockIdx.y * 8;
    const int b     = blockIdx.z;
    const short* hb = hS + (size_t)b * H * W * 64;

    float4v acc[2][2][2];   // [row][nt][mt]
    #pragma unroll
    for (int ri = 0; ri < 2; ri++)
        #pragma unroll
        for (int nt = 0; nt < 2; nt++)
            #pragma unroll
            for (int mt = 0; mt < 2; mt++)
                acc[ri][nt][mt] = (float4v){0.f, 0.f, 0.f, 0.f};

    float brg[2][4];
    #pragma unroll
    for (int mt = 0; mt < 2; mt++)
        #pragma unroll
        for (int r = 0; r < 4; r++) brg[mt][r] = bias[mt * 16 + q * 4 + r];

    for (int icc = 0; icc < 2; icc++) {
        const short* wfr = wfrag + (size_t)icc * 25600;
        short8 wbuf[2][5][2];
        // prologue: kx=0 column, issued before the staging barrier
        #pragma unroll
        for (int ky = 0; ky < 5; ky++) {
            wbuf[0][ky][0] = *(const short8*)(wfr + (((ky * 5) * 2 + 0) * 64 + lane) * 8);
            wbuf[0][ky][1] = *(const short8*)(wfr + (((ky * 5) * 2 + 1) * 64 + lane) * 8);
        }
        __syncthreads();
        for (int l = tid; l < 1728; l += 256) {      // 12*36*4 16B-chunks
            int qq  = l & 3;
            int pix = l >> 2;            // row*36+col
            int row = pix / 36;
            int col = pix - row * 36;
            int gy = ybase - 2 + row;
            int gx = xbase - 2 + col;
            short8 v = (short8)0;
            if ((unsigned)gy < (unsigned)H && (unsigned)gx < (unsigned)W)
                v = *(const short8*)(hb + ((size_t)gy * W + gx) * 64 + icc * 32 + qq * 8);
            *(short8*)(slab + pix * 40 + qq * 8) = v;
        }
        __syncthreads();

        #pragma unroll
        for (int kx = 0; kx < 5; kx++) {
            const int cur = kx & 1;
            if (kx < 4) {   // prefetch next kx column into the other buffer
                #pragma unroll
                for (int ky = 0; ky < 5; ky++) {
                    wbuf[cur ^ 1][ky][0] = *(const short8*)(wfr + (((ky * 5 + kx + 1) * 2 + 0) * 64 + lane) * 8);
                    wbuf[cur ^ 1][ky][1] = *(const short8*)(wfr + (((ky * 5 + kx + 1) * 2 + 1) * 64 + lane) * 8);
                }
            }
            #pragma unroll
            for (int t = 0; t < 6; t++) {
                const int boff = ((wv * 2 + t) * 36 + n + kx) * 40 + q * 8;
                short8 b0 = *(const short8*)(slab + boff);
                short8 b1 = *(const short8*)(slab + boff + 640);
                if (t <= 4) {   // row0: tap (ky=t, kx)
                    acc[0][0][0] = __builtin_amdgcn_mfma_f32_16x16x32_bf16(wbuf[cur][t][0], b0, acc[0][0][0], 0, 0, 0);
                    acc[0][0][1] = __builtin_amdgcn_mfma_f32_16x16x32_bf16(wbuf[cur][t][1], b0, acc[0][0][1], 0, 0, 0);
                    acc[0][1][0] = __builtin_amdgcn_mfma_f32_16x16x32_bf16(wbuf[cur][t][0], b1, acc[0][1][0], 0, 0, 0);
                    acc[0][1][1] = __builtin_amdgcn_mfma_f32_16x16x32_bf16(wbuf[cur][t][1], b1, acc[0][1][1], 0, 0, 0);
                }
                if (t >= 1) {   // row1: tap (ky=t-1, kx) — same regs, no reload
                    acc[1][0][0] = __builtin_amdgcn_mfma_f32_16x16x32_bf16(wbuf[cur][t - 1][0], b0, acc[1][0][0], 0, 0, 0);
                    acc[1][0][1] = __builtin_amdgcn_mfma_f32_16x16x32_bf16(wbuf[cur][t - 1][1], b0, acc[1][0][1], 0, 0, 0);
                    acc[1][1][0] = __builtin_amdgcn_mfma_f32_16x16x32_bf16(wbuf[cur][t - 1][0], b1, acc[1][1][0], 0, 0, 0);
                    acc[1][1][1] = __builtin_amdgcn_mfma_f32_16x16x32_bf16(wbuf[cur][t - 1][1], b1, acc[1][1][1], 0, 0, 0);
                }
            }
        }
    }

    #pragma unroll
    for (int ri = 0; ri < 2; ri++) {
        const int y = ybase + wv * 2 + ri;
        if (y < H) {
            #pragma unroll
            for (int nt = 0; nt < 2; nt++) {
                const int x = xbase + nt * 16 + n;
                if (x < W) {
                    short* cp = outc + (((size_t)b * H * W + (size_t)y * W + x) * 32);
                    #pragma unroll
                    for (int mt = 0; mt < 2; mt++) {
                        short4v o;
                        o.x = f2bs(fmaxf(acc[ri][nt][mt].x + brg[mt][0], 0.f));
                        o.y = f2bs(fmaxf(acc[ri][nt][mt].y + brg[mt][1], 0.f));
                        o.z = f2bs(fmaxf(acc[ri][nt][mt].z + brg[mt][2], 0.f));
                        o.w = f2bs(fmaxf(acc[ri][nt][mt].w + brg[mt][3], 0.f));
                        *(short4v*)(cp + mt * 16 + q * 4) = o;
                    }
                }
            }
        }
    }
}

// ---------------------------------------------------------------------------
// conv3 implicit-GEMM MFMA, 2 output rows per wave, 32px x 8row tile.
// IC=32 -> OC=1 (M padded to 16), +bias. Slab [12][36][40] = 34,560 B.
// Same kx-outer double-buffered weight registers as conv2.
// ---------------------------------------------------------------------------
__global__ __launch_bounds__(256, 4)
void conv3_k(const short* __restrict__ cP, const short* __restrict__ wf3,
             const float* __restrict__ bias, float* __restrict__ out,
             int H, int W) {
    __shared__ short slab[12 * 36 * 40];
    const int tid  = threadIdx.x;
    const int wv   = tid >> 6;
    const int lane = tid & 63;
    const int q    = lane >> 4;
    const int n    = lane & 15;
    const int xbase = blockIdx.x * 32;
    const int ybase = blockIdx.y * 8;
    const int b     = blockIdx.z;
    const short* cb = cP + (size_t)b * H * W * 32;

    short8 wbuf[2][5];
    #pragma unroll
    for (int ky = 0; ky < 5; ky++)
        wbuf[0][ky] = *(const short8*)(wf3 + (((ky * 5) * 64 + lane)) * 8);

    for (int l = tid; l < 1728; l += 256) {
        int qq  = l & 3;
        int pix = l >> 2;
        int row = pix / 36;
        int col = pix - row * 36;
        int gy = ybase - 2 + row;
        int gx = xbase - 2 + col;
        short8 v = (short8)0;
        if ((unsigned)gy < (unsigned)H && (unsigned)gx < (unsigned)W)
            v = *(const short8*)(cb + ((size_t)gy * W + gx) * 32 + qq * 8);
        *(short8*)(slab + pix * 40 + qq * 8) = v;
    }
    __syncthreads();

    float4v acc[2][2];
    #pragma unroll
    for (int ri = 0; ri < 2; ri++)
        #pragma unroll
        for (int nt = 0; nt < 2; nt++) acc[ri][nt] = (float4v){0.f, 0.f, 0.f, 0.f};

    #pragma unroll
    for (int kx = 0; kx < 5; kx++) {
        const int cur = kx & 1;
        if (kx < 4) {
            #pragma unroll
            for (int ky = 0; ky < 5; ky++)
                wbuf[cur ^ 1][ky] = *(const short8*)(wf3 + (((ky * 5 + kx + 1) * 64 + lane)) * 8);
        }
        #pragma unroll
        for (int t = 0; t < 6; t++) {
            const int boff = ((wv * 2 + t) * 36 + n + kx) * 40 + q * 8;
            short8 b0 = *(const short8*)(slab + boff);
            short8 b1 = *(const short8*)(slab + boff + 640);
            if (t <= 4) {
                acc[0][0] = __builtin_amdgcn_mfma_f32_16x16x32_bf16(wbuf[cur][t], b0, acc[0][0], 0, 0, 0);
                acc[0][1] = __builtin_amdgcn_mfma_f32_16x16x32_bf16(wbuf[cur][t], b1, acc[0][1], 0, 0, 0);
            }
            if (t >= 1) {
                acc[1][0] = __builtin_amdgcn_mfma_f32_16x16x32_bf16(wbuf[cur][t - 1], b0, acc[1][0], 0, 0, 0);
                acc[1][1] = __builtin_amdgcn_mfma_f32_16x16x32_bf16(wbuf[cur][t - 1], b1, acc[1][1], 0, 0, 0);
            }
        }
    }

    const float bi = bias[0];
    if (q == 0) {
        #pragma unroll
        for (int ri = 0; ri < 2; ri++) {
            const int y = ybase + wv * 2 + ri;
            if (y < H) {
                #pragma unroll
                for (int nt = 0; nt < 2; nt++) {
                    const int x = xbase + nt * 16 + n;
                    if (x < W) out[((size_t)b * H + y) * W + x] = acc[ri][nt].x + bi;
                }
            }
        }
    }
}

// ---------------------------------------------------------------------------
extern "C" void kernel_launch(void* const* d_in, const int* in_sizes, int n_in,
                              void* d_out, int out_size, void* d_ws, size_t ws_size,
                              hipStream_t stream) {
    const float* x        = (const float*)d_in[0];
    const float* elev0    = (const float*)d_in[1];
    const float* elev1    = (const float*)d_in[2];
    const int*   psi_idx1 = (const int*)  d_in[3];
    const float* psi_val1 = (const float*)d_in[4];
    const float* w1       = (const float*)d_in[5];
    const float* b1       = (const float*)d_in[6];
    const float* cw2_1    = (const float*)d_in[7];
    const float* cb2_1    = (const float*)d_in[8];
    const float* cw3_1    = (const float*)d_in[9];
    const float* cb3_1    = (const float*)d_in[10];
    const int*   psi_idx2 = (const int*)  d_in[11];
    const float* psi_val2 = (const float*)d_in[12];
    const float* w2       = (const float*)d_in[13];
    const float* b2       = (const float*)d_in[14];
    const float* cw2_2    = (const float*)d_in[15];
    const float* cb2_2    = (const float*)d_in[16];
    const float* cw3_2    = (const float*)d_in[17];
    const float* cb3_2    = (const float*)d_in[18];

    const int B = 4;
    const int H1 = 180, W1 = 360, P1 = H1 * W1;
    const int H2 = 360, W2 = 720, P2 = H2 * W2;

    // workspace layout (bytes); u2i overlaps the tail of c (stage-1 c uses
    // only the first 16.6 MB; u2i is dead before conv2_2 rewrites c).
    char* ws = (char*)d_ws;
    short* h    = (short*)(ws);                      // 132,710,400
    short* c    = (short*)(ws + 132710400);          //  66,355,200
    float* u2i  = (float*)(ws + 149299200);          //   8,294,400 (inside c tail)
    float* u1i  = (float*)(ws + 199065600);          //   2,073,600
    float* s1   = (float*)(ws + 201139200);          //   1,036,800
    short* wfA  = (short*)(ws + 202176000);          //     102,400
    short* wfB  = (short*)(ws + 202278400);          //     102,400
    short* wfD1 = (short*)(ws + 202380800);          //       4,096
    short* wfD2 = (short*)(ws + 202384896);          //       4,096
    short* wf31 = (short*)(ws + 202388992);          //      25,600
    short* wf32 = (short*)(ws + 202414592);          //      25,600
    (void)ws_size; (void)in_sizes; (void)n_in; (void)out_size;

    packall_k<<<(132096 + 255) / 256, 256, 0, stream>>>(
        cw2_1, cw2_2, cw3_1, cw3_2, w1, w2, wfA, wfB, wf31, wf32, wfD1, wfD2);

    // ---- stage 1 ----
    upsample_pack_k<<<(B * P1 + 255) / 256, 256, 0, stream>>>(x, elev0, u1i, B, 90, 180);
    disco_k<<<(P1 + 255) / 256, 256, 0, stream>>>(
        u1i, psi_idx1, psi_val1, wfD1, b1, h, P1);
    conv2_k<<<dim3((W1 + 31) / 32, (H1 + 7) / 8, B), 256, 0, stream>>>(
        h, wfA, cb2_1, c, H1, W1);
    conv3_k<<<dim3((W1 + 31) / 32, (H1 + 7) / 8, B), 256, 0, stream>>>(
        c, wf31, cb3_1, s1, H1, W1);

    // ---- stage 2 ----
    upsample_pack_k<<<(B * P2 + 255) / 256, 256, 0, stream>>>(s1, elev1, u2i, B, H1, W1);
    disco_k<<<(P2 + 255) / 256, 256, 0, stream>>>(
        u2i, psi_idx2, psi_val2, wfD2, b2, h, P2);
    conv2_k<<<dim3((W2 + 31) / 32, (H2 + 7) / 8, B), 256, 0, stream>>>(
        h, wfB, cb2_2, c, H2, W2);
    conv3_k<<<dim3((W2 + 31) / 32, (H2 + 7) / 8, B), 256, 0, stream>>>(
        c, wf32, cb3_2, (float*)d_out, H2, W2);
}